// Round 19
// baseline (1171.935 us; speedup 1.0000x reference)
//
#include <hip/hip_runtime.h>

// ---------------------------------------------------------------------------
// SparseEncoderResUNet on MI355X — round 19: wd1 instruction density.
// r18: 1123us; top = wd1 164us (VALUBusy 62%, ~5.5 instr per FMA: addr math
// per weight load + scalar loads). Fix: 64-thread blocks, lane = co-pair
// (float2 over 128 co), weights packed wd1P[t][ci][128] so ci-stride = 512B
// -> immediate-offset loads, float2 LDS reads. ~1.8 instr/FMA. Per-co
// accumulation order unchanged -> bit-identical. All else frozen from r18.
// ---------------------------------------------------------------------------

enum { EPI_MASK = 1, EPI_LEAKY = 2, EPI_RESID = 4 };
#define ROWCAP 32768

typedef short  bf16x8 __attribute__((ext_vector_type(8)));
typedef float  f32x4  __attribute__((ext_vector_type(4)));
typedef ushort us4    __attribute__((ext_vector_type(4)));

__device__ __forceinline__ float leaky(float v) { return v >= 0.f ? v : 0.2f * v; }
__device__ __forceinline__ ushort f2bf(float f) {
    unsigned u = __float_as_uint(f);
    return (ushort)((u + 0x7FFFu + ((u >> 16) & 1u)) >> 16);
}
__device__ __forceinline__ float bf2f(ushort h) {
    return __uint_as_float((unsigned)h << 16);
}
// channel c -> offset within a voxel's CI*2 block (interleaved hi/lo by 8)
__device__ __forceinline__ int choff(int c) {
    return (c >> 5) * 64 + ((c >> 3) & 3) * 16 + (c & 7);
}

// ---------------- weight transpose: w[co][cik] -> wT[cik][co] ----------------
__global__ __launch_bounds__(256) void transpose_w_kernel(
    const float* __restrict__ w, float* __restrict__ wT, int CO, int CIK)
{
    int i = blockIdx.x * 256 + threadIdx.x;
    if (i >= CO * CIK) return;
    int co = i / CIK, r = i - co * CIK;
    wT[(size_t)r * CO + co] = w[i];
}

// stage1b tap-major weights: w1bT[t][ci][co] = w1b[co][ci][t]
__global__ __launch_bounds__(256) void pack_w1b_kernel(
    const float* __restrict__ w, float* __restrict__ wT)
{
    int i = blockIdx.x * 256 + threadIdx.x;
    if (i >= 27 * 64 * 64) return;
    int co = i & 63, ci = (i >> 6) & 63, t = i >> 12;
    wT[i] = w[(co * 64 + ci) * 27 + t];
}

// wd1 tap-major weights: wd1P[t][ci][co] = wd1[co][ci][t]  (co=128, ci=64)
__global__ __launch_bounds__(256) void pack_wd1_kernel(
    const float* __restrict__ w, float* __restrict__ wP)
{
    int i = blockIdx.x * 256 + threadIdx.x;
    if (i >= 27 * 64 * 128) return;
    int co = i & 127, ci = (i >> 7) & 63, t = i >> 13;
    wP[i] = w[(co * 64 + ci) * 27 + t];
}

// ---------------- pack weights into MFMA A-frag layout, hi/lo interleaved ----
__global__ __launch_bounds__(256) void pack_w_kernel(
    const float* __restrict__ w, ushort* __restrict__ A, int CI, int CO)
{
    int i = blockIdx.x * 256 + threadIdx.x;
    if (i >= 27 * CI * CO * 2) return;
    int j = i & 7, hilo = (i >> 3) & 1, L = (i >> 4) & 63, rest = i >> 10;
    int NMT = CO >> 4, NCI = CI >> 5;
    int mt = rest % NMT; rest /= NMT;
    int ct = rest % NCI;
    int tap = rest / NCI;
    int co = mt * 16 + (L & 15);
    int ci = ct * 32 + (L >> 4) * 8 + j;
    float v = w[((size_t)co * CI + ci) * 27 + tap];
    ushort h = f2bf(v);
    A[i] = hilo ? f2bf(v - bf2f(h)) : h;
}

// ---------------- maxpool k3 s2 p1 (down_mask) ----------------
template<int DIN, int DOUT>
__global__ __launch_bounds__(256) void maxpool_kernel(
    const float* __restrict__ in, float* __restrict__ out)
{
    int i = blockIdx.x * 256 + threadIdx.x;
    constexpr int D3O = DOUT * DOUT * DOUT;
    if (i >= 2 * D3O) return;
    int b = i / D3O;
    int v = i - b * D3O;
    int z = v / (DOUT * DOUT), y = (v / DOUT) % DOUT, x = v % DOUT;
    float mx = 0.f;
    #pragma unroll
    for (int dz = 0; dz < 3; ++dz)
        #pragma unroll
        for (int dy = 0; dy < 3; ++dy)
            #pragma unroll
            for (int dx = 0; dx < 3; ++dx) {
                int zi = 2 * z - 1 + dz, yi = 2 * y - 1 + dy, xi = 2 * x - 1 + dx;
                if ((unsigned)zi < (unsigned)DIN && (unsigned)yi < (unsigned)DIN &&
                    (unsigned)xi < (unsigned)DIN)
                    mx = fmaxf(mx, in[(size_t)b * DIN * DIN * DIN + (zi * DIN + yi) * DIN + xi]);
            }
    out[i] = mx;
}

// ---------------- active-voxel list + dense index map ----------------
__global__ __launch_bounds__(256) void build_list_kernel(
    const float* __restrict__ m, int* __restrict__ list, int* __restrict__ idxmap,
    int* __restrict__ count)
{
    int i = blockIdx.x * 256 + threadIdx.x;
    if (i >= 2 * 262144) return;
    if (m[i] > 0.5f) {
        int k = atomicAdd(count, 1);
        if (k < ROWCAP) {
            list[k] = i;
            idxmap[i] = k;
        }
    }
}

// ---------------- stage1 conv-a (3->64, gathered) -> t1c[row][64] ----------------
__global__ __launch_bounds__(64) void stage1a_kernel(
    const float* __restrict__ x, const float* __restrict__ waT,
    const int* __restrict__ list, const int* __restrict__ count,
    float* __restrict__ t1c)
{
    __shared__ float smem[81];
    int n = min(*count, ROWCAP);
    for (int i = blockIdx.x; i < n; i += gridDim.x) {
        int lin = list[i];
        int b = lin >> 18;
        int v = lin & 262143;
        int z = v >> 12, y = (v >> 6) & 63, xx = v & 63;
        for (int j = threadIdx.x; j < 81; j += 64) {
            int ci = j / 27, t = j - ci * 27;
            int zz = z + t / 9 - 1, yy = y + (t / 3) % 3 - 1, xc = xx + t % 3 - 1;
            float val = 0.f;
            if ((unsigned)zz < 64u && (unsigned)yy < 64u && (unsigned)xc < 64u)
                val = x[(size_t)(b * 3 + ci) * 262144 + (zz << 12) + (yy << 6) + xc];
            smem[j] = val;
        }
        __syncthreads();
        float acc = 0.f;
        #pragma unroll 9
        for (int j = 0; j < 81; ++j)
            acc = fmaf(smem[j], waT[j * 64 + threadIdx.x], acc);
        t1c[(size_t)i * 64 + threadIdx.x] = leaky(acc);
        __syncthreads();
    }
}

// ---------------- stage1 conv-b v2: sparse taps, lanes = co -------------------
__global__ __launch_bounds__(64) void stage1b_kernel(
    const float* __restrict__ t1c, const float* __restrict__ x,
    const float* __restrict__ w1bT,  // [27][64][64] (tap, ci, co)
    const float* __restrict__ wdT,   // [3][64]
    const int* __restrict__ list, const int* __restrict__ idxmap,
    const int* __restrict__ count,
    float* __restrict__ x1c)
{
    __shared__ int   srr[27];
    __shared__ float sx[27][64];
    int n = min(*count, ROWCAP);
    int i = blockIdx.x;
    if (i >= n) return;
    const int tid = threadIdx.x;
    int lin = list[i];
    int b = lin >> 18;
    int v = lin & 262143;
    int z = v >> 12, y = (v >> 6) & 63, xx = v & 63;
    const int* im = idxmap + b * 262144;

    if (tid < 27) {
        int kz = tid / 9, ky = (tid / 3) % 3, kx = tid % 3;
        int zz = z + kz - 1, yy = y + ky - 1, xc = xx + kx - 1;
        int r = -1;
        if ((unsigned)zz < 64u && (unsigned)yy < 64u && (unsigned)xc < 64u)
            r = im[(zz << 12) + (yy << 6) + xc];
        srr[tid] = r;
    }
    __syncthreads();
    #pragma unroll 1
    for (int t = 0; t < 27; ++t) {
        int r = srr[t];
        if (r >= 0)
            sx[t][tid] = t1c[(size_t)r * 64 + tid];
    }
    __syncthreads();

    float acc = 0.f;
    #pragma unroll 1
    for (int t = 0; t < 27; ++t) {
        if (srr[t] < 0) continue;
        const float* wp = w1bT + (size_t)t * 4096 + tid;
        const float* xr = sx[t];
        #pragma unroll 8
        for (int ci = 0; ci < 64; ++ci)
            acc = fmaf(xr[ci], wp[ci * 64], acc);
    }
    float id = 0.f;
    #pragma unroll
    for (int ci = 0; ci < 3; ++ci)
        id = fmaf(x[(size_t)(b * 3 + ci) * 262144 + v], wdT[ci * 64 + tid], id);
    x1c[(size_t)i * 64 + tid] = leaky(acc + id);
}

// ---------------- wd1 v3: 64 threads, lane = co-pair, immediate-offset loads --
__global__ __launch_bounds__(64) void wd1_kernel(
    const float* __restrict__ x1c, const int* __restrict__ idxmap,
    const float* __restrict__ wP,   // [27][64][128] (tap, ci, co)
    ushort* __restrict__ outp)
{
    __shared__ int   srr[27];
    __shared__ float sx[27][64];
    const int tid = threadIdx.x;
    const int v = blockIdx.x;           // 0..32767
    const int b = blockIdx.y;
    const int zo = v >> 10, yo = (v >> 5) & 31, xo = v & 31;
    const int* im = idxmap + b * 262144;

    if (tid < 27) {
        int kz = tid / 9, ky = (tid / 3) % 3, kx = tid % 3;
        int zi = 2 * zo - 1 + kz, yi = 2 * yo - 1 + ky, xi = 2 * xo - 1 + kx;
        int r = -1;
        if ((unsigned)zi < 64u && (unsigned)yi < 64u && (unsigned)xi < 64u)
            r = im[(zi << 12) + (yi << 6) + xi];
        srr[tid] = r;
    }
    __syncthreads();
    #pragma unroll 1
    for (int t = 0; t < 27; ++t) {
        int r = srr[t];
        if (r >= 0)
            sx[t][tid] = x1c[(size_t)r * 64 + tid];
    }
    __syncthreads();

    float ax = 0.f, ay = 0.f;           // co = 2*tid, 2*tid+1
    #pragma unroll 1
    for (int t = 0; t < 27; ++t) {
        if (srr[t] < 0) continue;
        const float* wp = wP + (size_t)t * 8192 + 2 * tid;   // [t][ci][128]
        const float* xr = sx[t];
        #pragma unroll 4
        for (int ci = 0; ci < 64; ci += 2) {
            float2 s = *(const float2*)(xr + ci);
            float2 w0 = *(const float2*)(wp + ci * 128);
            float2 w1 = *(const float2*)(wp + (ci + 1) * 128);
            ax = fmaf(s.x, w0.x, ax);
            ay = fmaf(s.x, w0.y, ay);
            ax = fmaf(s.y, w1.x, ax);
            ay = fmaf(s.y, w1.y, ay);
        }
    }
    size_t vb = ((((size_t)b * 32 + zo) * 32 + yo) * 33 + xo) * 256 + 256;
    int c0 = 2 * tid;
    int off = choff(c0);                 // c0 even -> choff(c0+1) = off+1
    float v0 = leaky(ax), v1 = leaky(ay);
    ushort h0 = f2bf(v0), h1 = f2bf(v1);
    outp[vb + off]     = h0;
    outp[vb + off + 1] = h1;
    outp[vb + off + 8] = f2bf(v0 - bf2f(h0));
    outp[vb + off + 9] = f2bf(v1 - bf2f(h1));
}

// ---------------- MFMA conv v6: LDS-staged B (wd2) ----------------------------
template<int CI, int CO, int DI, int DO, int STRIDE, int RY, int NX, int NCT, int WPEU, int EPI>
__global__ __launch_bounds__(256, WPEU) void mfma_conv6_kernel(
    const ushort* __restrict__ inp, const ushort* __restrict__ A,
    const float* __restrict__ mask, const ushort* __restrict__ resid,
    ushort* __restrict__ outp)
{
    constexpr int NCI = CI / 32;
    constexpr int NMT = CO / 16;
    constexpr int CV = CI * 2;
    constexpr int CVO = CO * 2;
    constexpr int YG = DO / RY;
    constexpr int NXV = (DO - 1) * STRIDE + 3;
    constexpr int LVS = (STRIDE == 2) ? 68 : 72;
    constexpr int NGRP = RY * NXV * 8;

    __shared__ ushort sB[RY * NXV * LVS];

    const int rg = (blockIdx.x & 7) * ((int)gridDim.x >> 3) + (blockIdx.x >> 3);
    const int y0 = (rg % YG) * RY;
    const int z = (rg / YG) % DO;
    const int b = rg / (YG * DO);
    const int wave = threadIdx.x >> 6;
    const int lane = threadIdx.x & 63;
    const int n_l = lane & 15;
    const int q = lane >> 4;
    const int mt0 = (blockIdx.y * 4 + wave) * NCT;

    f32x4 acc[NCT][RY][NX];
    #pragma unroll
    for (int a = 0; a < NCT; ++a)
        #pragma unroll
        for (int r = 0; r < RY; ++r)
            #pragma unroll
            for (int c = 0; c < NX; ++c)
                acc[a][r][c] = (f32x4){0.f, 0.f, 0.f, 0.f};

    #pragma unroll 1
    for (int ct = 0; ct < NCI; ++ct) {
        #pragma unroll 1
        for (int dz = 0; dz < 3; ++dz) {
            int zp = z * STRIDE + dz - 1;
            bool vz = (unsigned)zp < (unsigned)DI;
            int zpc = vz ? zp : 0;
            #pragma unroll 1
            for (int dy = 0; dy < 3; ++dy) {
                long rowb[RY];
                #pragma unroll
                for (int ry = 0; ry < RY; ++ry) {
                    int yp = (y0 + ry) * STRIDE + dy - 1;
                    bool v = vz && ((unsigned)yp < (unsigned)DI);
                    rowb[ry] = v ? (((((long)b * DI + zpc) * DI + yp) * (DI + 1)) * CV + CV) : -1;
                }
                __syncthreads();
                for (int g = threadIdx.x; g < NGRP; g += 256) {
                    int r = g / (NXV * 8);
                    int rem = g - r * (NXV * 8);
                    int xv = rem >> 3;
                    int gg = rem & 7;
                    long src = (rowb[r] >= 0)
                             ? (rowb[r] + (long)(xv - 1) * CV + ct * 64 + gg * 8)
                             : (long)(ct * 64 + gg * 8);
                    *(bf16x8*)(sB + (r * NXV + xv) * LVS + gg * 8) = *(const bf16x8*)(inp + src);
                }
                __syncthreads();
                #pragma unroll
                for (int dx = 0; dx < 3; ++dx) {
                    const int tap = dz * 9 + dy * 3 + dx;
                    bf16x8 bh[RY][NX], bl[RY][NX];
                    #pragma unroll
                    for (int ry = 0; ry < RY; ++ry)
                        #pragma unroll
                        for (int nx = 0; nx < NX; ++nx) {
                            int xv = (nx * 16 + n_l) * STRIDE + dx;
                            const ushort* p = sB + (ry * NXV + xv) * LVS + q * 16;
                            bh[ry][nx] = *(const bf16x8*)p;
                            bl[ry][nx] = *(const bf16x8*)(p + 8);
                        }
                    bf16x8 ahf[NCT], alf[NCT];
                    #pragma unroll
                    for (int mt = 0; mt < NCT; ++mt) {
                        size_t aa = ((size_t)(tap * NCI + ct) * NMT + (mt0 + mt)) * 1024 + lane * 16;
                        ahf[mt] = *(const bf16x8*)(A + aa);
                        alf[mt] = *(const bf16x8*)(A + aa + 8);
                    }
                    #pragma unroll
                    for (int mt = 0; mt < NCT; ++mt)
                        #pragma unroll
                        for (int ry = 0; ry < RY; ++ry)
                            #pragma unroll
                            for (int nx = 0; nx < NX; ++nx)
                                acc[mt][ry][nx] = __builtin_amdgcn_mfma_f32_16x16x32_bf16(ahf[mt], bh[ry][nx], acc[mt][ry][nx], 0, 0, 0);
                    #pragma unroll
                    for (int mt = 0; mt < NCT; ++mt)
                        #pragma unroll
                        for (int ry = 0; ry < RY; ++ry)
                            #pragma unroll
                            for (int nx = 0; nx < NX; ++nx)
                                acc[mt][ry][nx] = __builtin_amdgcn_mfma_f32_16x16x32_bf16(ahf[mt], bl[ry][nx], acc[mt][ry][nx], 0, 0, 0);
                    #pragma unroll
                    for (int mt = 0; mt < NCT; ++mt)
                        #pragma unroll
                        for (int ry = 0; ry < RY; ++ry)
                            #pragma unroll
                            for (int nx = 0; nx < NX; ++nx)
                                acc[mt][ry][nx] = __builtin_amdgcn_mfma_f32_16x16x32_bf16(alf[mt], bh[ry][nx], acc[mt][ry][nx], 0, 0, 0);
                }
            }
        }
    }

    #pragma unroll
    for (int ry = 0; ry < RY; ++ry) {
        int yo = y0 + ry;
        #pragma unroll
        for (int nx = 0; nx < NX; ++nx) {
            int xo = nx * 16 + n_l;
            size_t vb = ((((size_t)b * DO + z) * DO + yo) * (DO + 1)) * CVO + CVO + (size_t)xo * CVO;
            float mval = 1.f;
            if (EPI & EPI_MASK) mval = mask[(((size_t)b * DO + z) * DO + yo) * DO + xo];
            #pragma unroll
            for (int mt = 0; mt < NCT; ++mt) {
                int c0 = (mt0 + mt) * 16 + q * 4;
                size_t oa = vb + choff(c0);
                float rs[4] = {0.f, 0.f, 0.f, 0.f};
                if (EPI & EPI_RESID) {
                    us4 rh4 = *(const us4*)(resid + oa);
                    us4 rl4 = *(const us4*)(resid + oa + 8);
                    #pragma unroll
                    for (int r = 0; r < 4; ++r) rs[r] = bf2f(rh4[r]) + bf2f(rl4[r]);
                }
                us4 oh, ol;
                #pragma unroll
                for (int r = 0; r < 4; ++r) {
                    float v = acc[mt][ry][nx][r];
                    if (EPI & EPI_MASK) v *= mval;
                    if (EPI & EPI_RESID) v += rs[r];
                    if (EPI & EPI_LEAKY) v = leaky(v);
                    ushort hb = f2bf(v);
                    oh[r] = hb;
                    ol[r] = f2bf(v - bf2f(hb));
                }
                *(us4*)(outp + oa) = oh;
                *(us4*)(outp + oa + 8) = ol;
            }
        }
    }
}

// ---------------- MFMA conv v8: stage-2 convs (S=1), slab staging -------------
template<int CI, int CO, int DI, int RY, int NX, int NCT, int WPEU, int EPI>
__global__ __launch_bounds__(256, WPEU) void mfma_conv8_kernel(
    const ushort* __restrict__ inp, const ushort* __restrict__ A,
    const float* __restrict__ mask, const ushort* __restrict__ resid,
    ushort* __restrict__ outp)
{
    constexpr int DO = DI;
    constexpr int NCI = CI / 32;
    constexpr int NMT = CO / 16;
    constexpr int CV = CI * 2;
    constexpr int CVO = CO * 2;
    constexpr int YG = DO / RY;
    constexpr int NYR = RY + 2;
    constexpr int NXV = DO + 2;
    constexpr int LVS = 72;
    constexpr int NGRP = NYR * NXV * 8;

    __shared__ ushort sB[NYR * NXV * LVS];

    const int rg = (blockIdx.x & 7) * ((int)gridDim.x >> 3) + (blockIdx.x >> 3);
    const int y0 = (rg % YG) * RY;
    const int z = (rg / YG) % DO;
    const int b = rg / (YG * DO);
    const int wave = threadIdx.x >> 6;
    const int lane = threadIdx.x & 63;
    const int n_l = lane & 15;
    const int q = lane >> 4;
    const int mt0 = (blockIdx.y * 4 + wave) * NCT;

    f32x4 acc[NCT][RY][NX];
    #pragma unroll
    for (int a = 0; a < NCT; ++a)
        #pragma unroll
        for (int r = 0; r < RY; ++r)
            #pragma unroll
            for (int c = 0; c < NX; ++c)
                acc[a][r][c] = (f32x4){0.f, 0.f, 0.f, 0.f};

    #pragma unroll 1
    for (int ct = 0; ct < NCI; ++ct) {
        #pragma unroll 1
        for (int dz = 0; dz < 3; ++dz) {
            int zp = z + dz - 1;
            bool vz = (unsigned)zp < (unsigned)DI;
            int zpc = vz ? zp : 0;
            __syncthreads();
            for (int g = threadIdx.x; g < NGRP; g += 256) {
                int r = g / (NXV * 8);
                int rem = g - r * (NXV * 8);
                int xv = rem >> 3;
                int gg = rem & 7;
                int yp = y0 + r - 1;
                bool v = vz & ((unsigned)yp < (unsigned)DI);
                long src = v ? ((((((long)b * DI + zpc) * DI + yp) * (DI + 1)) * CV + CV)
                                + (long)(xv - 1) * CV + ct * 64 + gg * 8)
                             : (long)(ct * 64 + gg * 8);   // zeroed lead pad
                *(bf16x8*)(sB + (r * NXV + xv) * LVS + gg * 8) = *(const bf16x8*)(inp + src);
            }
            __syncthreads();
            #pragma unroll 1
            for (int dy = 0; dy < 3; ++dy) {
                #pragma unroll
                for (int dx = 0; dx < 3; ++dx) {
                    const int tap = dz * 9 + dy * 3 + dx;
                    bf16x8 bh[RY][NX], bl[RY][NX];
                    #pragma unroll
                    for (int ry = 0; ry < RY; ++ry)
                        #pragma unroll
                        for (int nx = 0; nx < NX; ++nx) {
                            int xv = nx * 16 + n_l + dx;
                            const ushort* p = sB + ((ry + dy) * NXV + xv) * LVS + q * 16;
                            bh[ry][nx] = *(const bf16x8*)p;
                            bl[ry][nx] = *(const bf16x8*)(p + 8);
                        }
                    bf16x8 ahf[NCT], alf[NCT];
                    #pragma unroll
                    for (int mt = 0; mt < NCT; ++mt) {
                        size_t aa = ((size_t)(tap * NCI + ct) * NMT + (mt0 + mt)) * 1024 + lane * 16;
                        ahf[mt] = *(const bf16x8*)(A + aa);
                        alf[mt] = *(const bf16x8*)(A + aa + 8);
                    }
                    #pragma unroll
                    for (int mt = 0; mt < NCT; ++mt)
                        #pragma unroll
                        for (int ry = 0; ry < RY; ++ry)
                            #pragma unroll
                            for (int nx = 0; nx < NX; ++nx)
                                acc[mt][ry][nx] = __builtin_amdgcn_mfma_f32_16x16x32_bf16(ahf[mt], bh[ry][nx], acc[mt][ry][nx], 0, 0, 0);
                    #pragma unroll
                    for (int mt = 0; mt < NCT; ++mt)
                        #pragma unroll
                        for (int ry = 0; ry < RY; ++ry)
                            #pragma unroll
                            for (int nx = 0; nx < NX; ++nx)
                                acc[mt][ry][nx] = __builtin_amdgcn_mfma_f32_16x16x32_bf16(ahf[mt], bl[ry][nx], acc[mt][ry][nx], 0, 0, 0);
                    #pragma unroll
                    for (int mt = 0; mt < NCT; ++mt)
                        #pragma unroll
                        for (int ry = 0; ry < RY; ++ry)
                            #pragma unroll
                            for (int nx = 0; nx < NX; ++nx)
                                acc[mt][ry][nx] = __builtin_amdgcn_mfma_f32_16x16x32_bf16(alf[mt], bh[ry][nx], acc[mt][ry][nx], 0, 0, 0);
                }
            }
        }
    }

    #pragma unroll
    for (int ry = 0; ry < RY; ++ry) {
        int yo = y0 + ry;
        #pragma unroll
        for (int nx = 0; nx < NX; ++nx) {
            int xo = nx * 16 + n_l;
            size_t vb = ((((size_t)b * DO + z) * DO + yo) * (DO + 1)) * CVO + CVO + (size_t)xo * CVO;
            float mval = 1.f;
            if (EPI & EPI_MASK) mval = mask[(((size_t)b * DO + z) * DO + yo) * DO + xo];
            #pragma unroll
            for (int mt = 0; mt < NCT; ++mt) {
                int c0 = (mt0 + mt) * 16 + q * 4;
                size_t oa = vb + choff(c0);
                float rs[4] = {0.f, 0.f, 0.f, 0.f};
                if (EPI & EPI_RESID) {
                    us4 rh4 = *(const us4*)(resid + oa);
                    us4 rl4 = *(const us4*)(resid + oa + 8);
                    #pragma unroll
                    for (int r = 0; r < 4; ++r) rs[r] = bf2f(rh4[r]) + bf2f(rl4[r]);
                }
                us4 oh, ol;
                #pragma unroll
                for (int r = 0; r < 4; ++r) {
                    float v = acc[mt][ry][nx][r];
                    if (EPI & EPI_MASK) v *= mval;
                    if (EPI & EPI_RESID) v += rs[r];
                    if (EPI & EPI_LEAKY) v = leaky(v);
                    ushort hb = f2bf(v);
                    oh[r] = hb;
                    ol[r] = f2bf(v - bf2f(hb));
                }
                *(us4*)(outp + oa) = oh;
                *(us4*)(outp + oa + 8) = ol;
            }
        }
    }
}

// ---------------- MFMA conv v7: stage-3 convs (S=1, DO=16), K-split ----------
template<int CI, int CO, int DI, int RY, int NCT, int KS, int WPEU>
__global__ __launch_bounds__(256, WPEU) void mfma_conv7_kernel(
    const ushort* __restrict__ inp, const ushort* __restrict__ A,
    float* __restrict__ part)
{
    constexpr int DO = DI;
    constexpr int NCI = CI / 32;
    constexpr int KCI = NCI / KS;
    constexpr int NMT = CO / 16;
    constexpr int CV = CI * 2;
    constexpr int YG = DO / RY;
    constexpr int NYR = RY + 2;
    constexpr int NXV = DO + 2;
    constexpr int LVS = 72;
    constexpr int NCOG = NMT / (4 * NCT);
    constexpr int D3 = DO * DO * DO;

    __shared__ ushort sB[3 * NYR * NXV * LVS];

    const int rg = (blockIdx.x & 7) * ((int)gridDim.x >> 3) + (blockIdx.x >> 3);
    const int y0 = (rg % YG) * RY;
    const int z = (rg / YG) % DO;
    const int b = rg / (YG * DO);
    const int wave = threadIdx.x >> 6;
    const int lane = threadIdx.x & 63;
    const int n_l = lane & 15;
    const int q = lane >> 4;
    const int cog = blockIdx.y % NCOG;
    const int kc = blockIdx.y / NCOG;
    const int mt0 = (cog * 4 + wave) * NCT;

    f32x4 acc[NCT][RY];
    #pragma unroll
    for (int a = 0; a < NCT; ++a)
        #pragma unroll
        for (int r = 0; r < RY; ++r)
            acc[a][r] = (f32x4){0.f, 0.f, 0.f, 0.f};

    #pragma unroll 1
    for (int ctl = 0; ctl < KCI; ++ctl) {
        const int ct = kc * KCI + ctl;
        __syncthreads();
        for (int g = threadIdx.x; g < 3 * NYR * NXV * 8; g += 256) {
            int row = g / (NXV * 8);
            int rem = g - row * (NXV * 8);
            int xv = rem >> 3;
            int gg = rem & 7;
            int zi = row / NYR, yr = row - zi * NYR;
            int zp = z + zi - 1;
            int yp = y0 + yr - 1;
            bool v = ((unsigned)zp < (unsigned)DI) & ((unsigned)yp < (unsigned)DI);
            long src = v ? ((((((long)b * DI + zp) * DI + yp) * (DI + 1)) * CV + CV)
                            + (long)(xv - 1) * CV + ct * 64 + gg * 8)
                         : (long)(ct * 64 + gg * 8);
            *(bf16x8*)(sB + (row * NXV + xv) * LVS + gg * 8) = *(const bf16x8*)(inp + src);
        }
        __syncthreads();
        #pragma unroll 1
        for (int dz = 0; dz < 3; ++dz) {
            #pragma unroll 1
            for (int dy = 0; dy < 3; ++dy) {
                #pragma unroll
                for (int dx = 0; dx < 3; ++dx) {
                    const int tap = dz * 9 + dy * 3 + dx;
                    bf16x8 bh[RY], bl[RY];
                    #pragma unroll
                    for (int ry = 0; ry < RY; ++ry) {
                        const ushort* p = sB + ((dz * NYR + ry + dy) * NXV + n_l + dx) * LVS + q * 16;
                        bh[ry] = *(const bf16x8*)p;
                        bl[ry] = *(const bf16x8*)(p + 8);
                    }
                    bf16x8 ahf[NCT], alf[NCT];
                    #pragma unroll
                    for (int mt = 0; mt < NCT; ++mt) {
                        size_t aa = ((size_t)(tap * NCI + ct) * NMT + (mt0 + mt)) * 1024 + lane * 16;
                        ahf[mt] = *(const bf16x8*)(A + aa);
                        alf[mt] = *(const bf16x8*)(A + aa + 8);
                    }
                    #pragma unroll
                    for (int mt = 0; mt < NCT; ++mt)
                        #pragma unroll
                        for (int ry = 0; ry < RY; ++ry)
                            acc[mt][ry] = __builtin_amdgcn_mfma_f32_16x16x32_bf16(ahf[mt], bh[ry], acc[mt][ry], 0, 0, 0);
                    #pragma unroll
                    for (int mt = 0; mt < NCT; ++mt)
                        #pragma unroll
                        for (int ry = 0; ry < RY; ++ry)
                            acc[mt][ry] = __builtin_amdgcn_mfma_f32_16x16x32_bf16(ahf[mt], bl[ry], acc[mt][ry], 0, 0, 0);
                    #pragma unroll
                    for (int mt = 0; mt < NCT; ++mt)
                        #pragma unroll
                        for (int ry = 0; ry < RY; ++ry)
                            acc[mt][ry] = __builtin_amdgcn_mfma_f32_16x16x32_bf16(alf[mt], bh[ry], acc[mt][ry], 0, 0, 0);
                }
            }
        }
    }

    #pragma unroll
    for (int ry = 0; ry < RY; ++ry) {
        int yo = y0 + ry;
        int v = (z * DO + yo) * DO + n_l;
        #pragma unroll
        for (int mt = 0; mt < NCT; ++mt) {
            int c0 = (mt0 + mt) * 16 + q * 4;
            size_t off = (((size_t)kc * 2 + b) * D3 + v) * CO + c0;
            *(f32x4*)(part + off) = acc[mt][ry];
        }
    }
}

// ---------------- combine3: sum K-split halves + epilogue -> interleaved CL ---
__global__ __launch_bounds__(256) void combine3_kernel(
    const float* __restrict__ part, const float* __restrict__ mask,
    const ushort* __restrict__ resid, ushort* __restrict__ outp)
{
    int i = blockIdx.x * 256 + threadIdx.x;      // over 2*4096*64
    if (i >= 2 * 4096 * 64) return;
    int g = i & 63, v = (i >> 6) & 4095, b = i >> 18;
    int c0 = g * 4;
    size_t p0 = (((size_t)b) * 4096 + v) * 256 + c0;
    float4 s0 = *(const float4*)(part + p0);
    float4 s1 = *(const float4*)(part + p0 + (size_t)2 * 4096 * 256);
    float m = mask[b * 4096 + v];
    int z = v >> 8, y = (v >> 4) & 15, x = v & 15;
    size_t vb = ((((size_t)b * 16 + z) * 16 + y) * 17) * 512 + 512 + (size_t)x * 512;
    size_t oa = vb + choff(c0);
    float rs[4] = {0.f, 0.f, 0.f, 0.f};
    if (resid) {
        us4 rh = *(const us4*)(resid + oa);
        us4 rl = *(const us4*)(resid + oa + 8);
        #pragma unroll
        for (int r = 0; r < 4; ++r) rs[r] = bf2f(rh[r]) + bf2f(rl[r]);
    }
    float sv[4] = {s0.x + s1.x, s0.y + s1.y, s0.z + s1.z, s0.w + s1.w};
    us4 oh, ol;
    #pragma unroll
    for (int r = 0; r < 4; ++r) {
        float val = sv[r] * m + rs[r];
        val = leaky(val);
        ushort hb = f2bf(val);
        oh[r] = hb;
        ol[r] = f2bf(val - bf2f(hb));
    }
    *(us4*)(outp + oa) = oh;
    *(us4*)(outp + oa + 8) = ol;
}

// ---------------- wd3 via MFMA (product-major) -> x4 fp32 ---------------------
__global__ __launch_bounds__(256) void wd3_mfma_kernel(
    const ushort* __restrict__ x3, const ushort* __restrict__ A,
    float* __restrict__ x4)
{
    constexpr int NCI = 8;   // 256/32
    constexpr int NMT = 8;   // 128/16
    const int blk = blockIdx.x;
    const int yg = blk & 3;
    const int z = (blk >> 2) & 7;
    const int b = blk >> 5;
    const int wave = threadIdx.x >> 6;
    const int lane = threadIdx.x & 63;
    const int n_l = lane & 15;
    const int q = lane >> 4;
    const int y = yg * 2 + (n_l >> 3);
    const int x = n_l & 7;
    const int mt0 = wave * 2;

    f32x4 acc[2];
    acc[0] = (f32x4){0.f, 0.f, 0.f, 0.f};
    acc[1] = (f32x4){0.f, 0.f, 0.f, 0.f};
    const bf16x8 zero8 = {0, 0, 0, 0, 0, 0, 0, 0};

    for (int ct = 0; ct < NCI; ++ct) {
        #pragma unroll
        for (int dz = 0; dz < 3; ++dz) {
            int zp = 2 * z + dz - 1;
            if ((unsigned)zp >= 16u) continue;
            #pragma unroll
            for (int dy = 0; dy < 3; ++dy) {
                int yp = 2 * y + dy - 1;
                bool vy = (unsigned)yp < 16u;
                int ypc = vy ? yp : 0;
                #pragma unroll
                for (int dx = 0; dx < 3; ++dx) {
                    int xp = 2 * x + dx - 1;
                    int tap = dz * 9 + dy * 3 + dx;
                    size_t ba = ((((size_t)b * 16 + zp) * 16 + ypc) * 17 + 1 + xp) * 512
                              + ct * 64 + q * 16;
                    bf16x8 bh = vy ? *(const bf16x8*)(x3 + ba) : zero8;
                    bf16x8 bl = vy ? *(const bf16x8*)(x3 + ba + 8) : zero8;
                    bf16x8 ahf[2], alf[2];
                    #pragma unroll
                    for (int mt = 0; mt < 2; ++mt) {
                        size_t aa = ((size_t)(tap * NCI + ct) * NMT + (mt0 + mt)) * 1024 + lane * 16;
                        ahf[mt] = *(const bf16x8*)(A + aa);
                        alf[mt] = *(const bf16x8*)(A + aa + 8);
                    }
                    #pragma unroll
                    for (int mt = 0; mt < 2; ++mt)
                        acc[mt] = __builtin_amdgcn_mfma_f32_16x16x32_bf16(ahf[mt], bh, acc[mt], 0, 0, 0);
                    #pragma unroll
                    for (int mt = 0; mt < 2; ++mt)
                        acc[mt] = __builtin_amdgcn_mfma_f32_16x16x32_bf16(ahf[mt], bl, acc[mt], 0, 0, 0);
                    #pragma unroll
                    for (int mt = 0; mt < 2; ++mt)
                        acc[mt] = __builtin_amdgcn_mfma_f32_16x16x32_bf16(alf[mt], bh, acc[mt], 0, 0, 0);
                }
            }
        }
    }
    #pragma unroll
    for (int mt = 0; mt < 2; ++mt)
        #pragma unroll
        for (int r = 0; r < 4; ++r) {
            int co = (mt0 + mt) * 16 + q * 4 + r;
            x4[((size_t)(b * 128 + co)) * 512 + z * 64 + y * 8 + x] = leaky(acc[mt][r]);
        }
}

// ---------------- final: mean/max pool over 8^3 -------------------------------
__global__ __launch_bounds__(64) void reduce_kernel(
    const float* __restrict__ x4, float* __restrict__ out)
{
    int bc = blockIdx.x;
    int b = bc >> 7, c = bc & 127;
    const float* p = x4 + (size_t)(b * 128 + c) * 512;
    float s = 0.f, mx = -3.4e38f;
    for (int i = threadIdx.x; i < 512; i += 64) {
        float v = p[i];
        s += v;
        mx = fmaxf(mx, v);
    }
    #pragma unroll
    for (int o = 32; o > 0; o >>= 1) {
        s += __shfl_down(s, o);
        mx = fmaxf(mx, __shfl_down(mx, o));
    }
    if (threadIdx.x == 0) {
        out[b * 256 + c] = s * (1.f / 512.f);
        out[b * 256 + 128 + c] = mx;
    }
}

__global__ __launch_bounds__(256) void zero_out_kernel(float* __restrict__ out, int n)
{
    int i = blockIdx.x * 256 + threadIdx.x;
    if (i < n) out[i] = 0.f;
}

// ---------------------------------------------------------------------------
extern "C" void kernel_launch(void* const* d_in, const int* in_sizes, int n_in,
                              void* d_out, int out_size, void* d_ws, size_t ws_size,
                              hipStream_t stream)
{
    (void)in_sizes; (void)n_in;
    const float* x    = (const float*)d_in[0];
    const float* mask = (const float*)d_in[1];
    const float* w1a  = (const float*)d_in[2];
    const float* w1b  = (const float*)d_in[3];
    const float* w1d  = (const float*)d_in[4];
    const float* wd1  = (const float*)d_in[5];
    const float* w2a  = (const float*)d_in[6];
    const float* w2b  = (const float*)d_in[7];
    const float* wd2  = (const float*)d_in[8];
    const float* w3a  = (const float*)d_in[9];
    const float* w3b  = (const float*)d_in[10];
    const float* wd3  = (const float*)d_in[11];
    float* out = (float*)d_out;
    char* ws = (char*)d_ws;

    const size_t RSZ = 34603520;      // stage-2 tensor region (interleaved)
    const size_t SZ3 = 8913920;       // stage-3 tensor bytes
    const size_t POFF = 9437184;      // partial-buffer offset within R2/R3
    char* R1 = ws;
    char* R2 = ws + RSZ;
    char* R3 = ws + 2 * RSZ;
    size_t off = 3 * RSZ;
    auto alloc = [&](size_t bytes) { char* p = ws + off; off = (off + bytes + 255) & ~255ull; return p; };
    ushort* pk2a = (ushort*)alloc(1769472);
    ushort* pk2b = (ushort*)alloc(1769472);
    ushort* pkd2 = (ushort*)alloc(3538944);
    ushort* pk3a = (ushort*)alloc(7077888);
    ushort* pk3b = (ushort*)alloc(7077888);
    float*  wd1P = (float*)alloc(884736);
    float*  waT  = (float*)alloc(20736);
    float*  w1bT = (float*)alloc(442368);
    float*  wdTt = (float*)alloc(768);
    float*  m2   = (float*)alloc(262144);
    float*  m3   = (float*)alloc(32768);
    int*    cnt  = (int*)alloc(256);
    const size_t NEED = off;

    if (ws_size < NEED) {
        zero_out_kernel<<<dim3((out_size + 255) / 256), 256, 0, stream>>>(out, out_size);
        return;
    }

    // stage-1 scratch aliased into R2 (dead before t2 is written)
    float* t1c  = (float*)R2;
    float* x1c  = (float*)(R2 + 8388608);
    int*   idx  = (int*)(R2 + 16777216);
    int*   list = (int*)(R2 + 18874368);
    // late-phase aliases
    ushort* pkd3 = (ushort*)R1;       // xin3 dead after conv3b combine
    float*  x4   = (float*)R2;        // t3 dead after conv3b conv
    float*  part3a = (float*)(R2 + POFF);
    float*  part3b = (float*)(R3 + POFF);

    ushort* xin2 = (ushort*)R1;
    ushort* t2   = (ushort*)R2;
    ushort* x2   = (ushort*)R3;
    ushort* xin3 = (ushort*)R1;
    ushort* t3   = (ushort*)R2;
    ushort* x3   = (ushort*)R3;

    hipMemsetAsync(cnt, 0, 4, stream);
    hipMemsetAsync(idx, 0xFF, 2097152, stream);
    hipMemsetAsync(R1, 0, RSZ, stream);           // xin2 pads

    auto tg = [](int n) { return dim3((n + 255) / 256); };
    pack_w_kernel<<<tg(27 * 128 * 128 * 2), 256, 0, stream>>>(w2a, pk2a, 128, 128);
    pack_w_kernel<<<tg(27 * 128 * 128 * 2), 256, 0, stream>>>(w2b, pk2b, 128, 128);
    pack_w_kernel<<<tg(27 * 128 * 256 * 2), 256, 0, stream>>>(wd2, pkd2, 128, 256);
    pack_w_kernel<<<tg(27 * 256 * 256 * 2), 256, 0, stream>>>(w3a, pk3a, 256, 256);
    pack_w_kernel<<<tg(27 * 256 * 256 * 2), 256, 0, stream>>>(w3b, pk3b, 256, 256);
    pack_wd1_kernel    <<<tg(27 * 64 * 128), 256, 0, stream>>>(wd1, wd1P);
    transpose_w_kernel <<<tg(64 * 81),    256, 0, stream>>>(w1a, waT,  64, 81);
    pack_w1b_kernel    <<<tg(27 * 64 * 64), 256, 0, stream>>>(w1b, w1bT);
    transpose_w_kernel <<<tg(64 * 3),     256, 0, stream>>>(w1d, wdTt, 64, 3);

    maxpool_kernel<64, 32><<<dim3(2 * 32768 / 256), 256, 0, stream>>>(mask, m2);
    maxpool_kernel<32, 16><<<dim3(2 * 4096 / 256),  256, 0, stream>>>(m2, m3);
    build_list_kernel<<<dim3(2 * 262144 / 256), 256, 0, stream>>>(mask, list, idx, cnt);

    // stage 1 (sparse, fp32)
    stage1a_kernel<<<dim3(2048), 64, 0, stream>>>(x, waT, list, cnt, t1c);
    stage1b_kernel<<<dim3(ROWCAP), 64, 0, stream>>>(t1c, x, w1bT, wdTt, list, idx, cnt, x1c);
    wd1_kernel<<<dim3(32768, 2), 64, 0, stream>>>(x1c, idx, wd1P, xin2);

    // stage-1 scratch dead; clear R2/R3 (t2/x2 pads)
    hipMemsetAsync(R2, 0, RSZ, stream);
    hipMemsetAsync(R3, 0, RSZ, stream);

    // stage2 res block: conv8 slab staging (RY=2/NX=2/NCT=2, 1024 blocks)
    mfma_conv8_kernel<128, 128, 32, 2, 2, 2, 4, EPI_MASK | EPI_LEAKY>
        <<<dim3(1024, 1), 256, 0, stream>>>(xin2, pk2a, m2, nullptr, t2);
    mfma_conv8_kernel<128, 128, 32, 2, 2, 2, 4, EPI_MASK | EPI_RESID | EPI_LEAKY>
        <<<dim3(1024, 1), 256, 0, stream>>>(t2, pk2b, m2, xin2, x2);

    // xin2 dead -> clear xin3 area; wd2 (conv6)
    hipMemsetAsync(R1, 0, SZ3, stream);
    mfma_conv6_kernel<128, 256, 32, 16, 2, 2, 1, 2, 4, EPI_LEAKY>
        <<<dim3(256, 2), 256, 0, stream>>>(x2, pkd2, nullptr, nullptr, xin3);

    // conv3a: conv7 (K-split) -> partials; combine -> t3
    hipMemsetAsync(R2, 0, SZ3, stream);
    mfma_conv7_kernel<256, 256, 16, 2, 2, 2, 4>
        <<<dim3(256, 4), 256, 0, stream>>>(xin3, pk3a, part3a);
    combine3_kernel<<<dim3(2048), 256, 0, stream>>>(part3a, m3, nullptr, t3);

    // conv3b: conv7 -> partials; combine (resid=xin3) -> x3
    hipMemsetAsync(R3, 0, SZ3, stream);
    mfma_conv7_kernel<256, 256, 16, 2, 2, 2, 4>
        <<<dim3(256, 4), 256, 0, stream>>>(t3, pk3b, part3b);
    combine3_kernel<<<dim3(2048), 256, 0, stream>>>(part3b, m3, xin3, x3);

    // xin3 (R1) and t3 (R2) dead: pack wd3 -> R1, MFMA wd3 -> x4 (R2)
    pack_w_kernel<<<tg(27 * 256 * 128 * 2), 256, 0, stream>>>(wd3, pkd3, 256, 128);
    wd3_mfma_kernel<<<dim3(64), 256, 0, stream>>>(x3, pkd3, x4);

    reduce_kernel<<<dim3(256), 64, 0, stream>>>(x4, out);
}

// Round 20
// 1120.551 us; speedup vs baseline: 1.0459x; 1.0459x over previous
//
#include <hip/hip_runtime.h>

// ---------------------------------------------------------------------------
// SparseEncoderResUNet on MI355X — round 20: wd1 hybrid (r18 occupancy +
// r19 packed weights). r19 REGRESSED (164->187us): 64-thr blocks halved
// occupancy (77->47%) and exposed weight-load latency. This round: 128-thr
// lane=co structure (r18) with wd1P[t][ci][128] weights (constant 512B ci
// stride -> immediate-offset loads, ~2.2 instr/FMA). Per-co accumulation
// order unchanged -> bit-identical. Everything else frozen from r18.
// ---------------------------------------------------------------------------

enum { EPI_MASK = 1, EPI_LEAKY = 2, EPI_RESID = 4 };
#define ROWCAP 32768

typedef short  bf16x8 __attribute__((ext_vector_type(8)));
typedef float  f32x4  __attribute__((ext_vector_type(4)));
typedef ushort us4    __attribute__((ext_vector_type(4)));

__device__ __forceinline__ float leaky(float v) { return v >= 0.f ? v : 0.2f * v; }
__device__ __forceinline__ ushort f2bf(float f) {
    unsigned u = __float_as_uint(f);
    return (ushort)((u + 0x7FFFu + ((u >> 16) & 1u)) >> 16);
}
__device__ __forceinline__ float bf2f(ushort h) {
    return __uint_as_float((unsigned)h << 16);
}
// channel c -> offset within a voxel's CI*2 block (interleaved hi/lo by 8)
__device__ __forceinline__ int choff(int c) {
    return (c >> 5) * 64 + ((c >> 3) & 3) * 16 + (c & 7);
}

// ---------------- weight transpose: w[co][cik] -> wT[cik][co] ----------------
__global__ __launch_bounds__(256) void transpose_w_kernel(
    const float* __restrict__ w, float* __restrict__ wT, int CO, int CIK)
{
    int i = blockIdx.x * 256 + threadIdx.x;
    if (i >= CO * CIK) return;
    int co = i / CIK, r = i - co * CIK;
    wT[(size_t)r * CO + co] = w[i];
}

// stage1b tap-major weights: w1bT[t][ci][co] = w1b[co][ci][t]
__global__ __launch_bounds__(256) void pack_w1b_kernel(
    const float* __restrict__ w, float* __restrict__ wT)
{
    int i = blockIdx.x * 256 + threadIdx.x;
    if (i >= 27 * 64 * 64) return;
    int co = i & 63, ci = (i >> 6) & 63, t = i >> 12;
    wT[i] = w[(co * 64 + ci) * 27 + t];
}

// wd1 tap-major weights: wd1P[t][ci][co] = wd1[co][ci][t]  (co=128, ci=64)
__global__ __launch_bounds__(256) void pack_wd1_kernel(
    const float* __restrict__ w, float* __restrict__ wP)
{
    int i = blockIdx.x * 256 + threadIdx.x;
    if (i >= 27 * 64 * 128) return;
    int co = i & 127, ci = (i >> 7) & 63, t = i >> 13;
    wP[i] = w[(co * 64 + ci) * 27 + t];
}

// ---------------- pack weights into MFMA A-frag layout, hi/lo interleaved ----
__global__ __launch_bounds__(256) void pack_w_kernel(
    const float* __restrict__ w, ushort* __restrict__ A, int CI, int CO)
{
    int i = blockIdx.x * 256 + threadIdx.x;
    if (i >= 27 * CI * CO * 2) return;
    int j = i & 7, hilo = (i >> 3) & 1, L = (i >> 4) & 63, rest = i >> 10;
    int NMT = CO >> 4, NCI = CI >> 5;
    int mt = rest % NMT; rest /= NMT;
    int ct = rest % NCI;
    int tap = rest / NCI;
    int co = mt * 16 + (L & 15);
    int ci = ct * 32 + (L >> 4) * 8 + j;
    float v = w[((size_t)co * CI + ci) * 27 + tap];
    ushort h = f2bf(v);
    A[i] = hilo ? f2bf(v - bf2f(h)) : h;
}

// ---------------- maxpool k3 s2 p1 (down_mask) ----------------
template<int DIN, int DOUT>
__global__ __launch_bounds__(256) void maxpool_kernel(
    const float* __restrict__ in, float* __restrict__ out)
{
    int i = blockIdx.x * 256 + threadIdx.x;
    constexpr int D3O = DOUT * DOUT * DOUT;
    if (i >= 2 * D3O) return;
    int b = i / D3O;
    int v = i - b * D3O;
    int z = v / (DOUT * DOUT), y = (v / DOUT) % DOUT, x = v % DOUT;
    float mx = 0.f;
    #pragma unroll
    for (int dz = 0; dz < 3; ++dz)
        #pragma unroll
        for (int dy = 0; dy < 3; ++dy)
            #pragma unroll
            for (int dx = 0; dx < 3; ++dx) {
                int zi = 2 * z - 1 + dz, yi = 2 * y - 1 + dy, xi = 2 * x - 1 + dx;
                if ((unsigned)zi < (unsigned)DIN && (unsigned)yi < (unsigned)DIN &&
                    (unsigned)xi < (unsigned)DIN)
                    mx = fmaxf(mx, in[(size_t)b * DIN * DIN * DIN + (zi * DIN + yi) * DIN + xi]);
            }
    out[i] = mx;
}

// ---------------- active-voxel list + dense index map ----------------
__global__ __launch_bounds__(256) void build_list_kernel(
    const float* __restrict__ m, int* __restrict__ list, int* __restrict__ idxmap,
    int* __restrict__ count)
{
    int i = blockIdx.x * 256 + threadIdx.x;
    if (i >= 2 * 262144) return;
    if (m[i] > 0.5f) {
        int k = atomicAdd(count, 1);
        if (k < ROWCAP) {
            list[k] = i;
            idxmap[i] = k;
        }
    }
}

// ---------------- stage1 conv-a (3->64, gathered) -> t1c[row][64] ----------------
__global__ __launch_bounds__(64) void stage1a_kernel(
    const float* __restrict__ x, const float* __restrict__ waT,
    const int* __restrict__ list, const int* __restrict__ count,
    float* __restrict__ t1c)
{
    __shared__ float smem[81];
    int n = min(*count, ROWCAP);
    for (int i = blockIdx.x; i < n; i += gridDim.x) {
        int lin = list[i];
        int b = lin >> 18;
        int v = lin & 262143;
        int z = v >> 12, y = (v >> 6) & 63, xx = v & 63;
        for (int j = threadIdx.x; j < 81; j += 64) {
            int ci = j / 27, t = j - ci * 27;
            int zz = z + t / 9 - 1, yy = y + (t / 3) % 3 - 1, xc = xx + t % 3 - 1;
            float val = 0.f;
            if ((unsigned)zz < 64u && (unsigned)yy < 64u && (unsigned)xc < 64u)
                val = x[(size_t)(b * 3 + ci) * 262144 + (zz << 12) + (yy << 6) + xc];
            smem[j] = val;
        }
        __syncthreads();
        float acc = 0.f;
        #pragma unroll 9
        for (int j = 0; j < 81; ++j)
            acc = fmaf(smem[j], waT[j * 64 + threadIdx.x], acc);
        t1c[(size_t)i * 64 + threadIdx.x] = leaky(acc);
        __syncthreads();
    }
}

// ---------------- stage1 conv-b v2: sparse taps, lanes = co -------------------
__global__ __launch_bounds__(64) void stage1b_kernel(
    const float* __restrict__ t1c, const float* __restrict__ x,
    const float* __restrict__ w1bT,  // [27][64][64] (tap, ci, co)
    const float* __restrict__ wdT,   // [3][64]
    const int* __restrict__ list, const int* __restrict__ idxmap,
    const int* __restrict__ count,
    float* __restrict__ x1c)
{
    __shared__ int   srr[27];
    __shared__ float sx[27][64];
    int n = min(*count, ROWCAP);
    int i = blockIdx.x;
    if (i >= n) return;
    const int tid = threadIdx.x;
    int lin = list[i];
    int b = lin >> 18;
    int v = lin & 262143;
    int z = v >> 12, y = (v >> 6) & 63, xx = v & 63;
    const int* im = idxmap + b * 262144;

    if (tid < 27) {
        int kz = tid / 9, ky = (tid / 3) % 3, kx = tid % 3;
        int zz = z + kz - 1, yy = y + ky - 1, xc = xx + kx - 1;
        int r = -1;
        if ((unsigned)zz < 64u && (unsigned)yy < 64u && (unsigned)xc < 64u)
            r = im[(zz << 12) + (yy << 6) + xc];
        srr[tid] = r;
    }
    __syncthreads();
    #pragma unroll 1
    for (int t = 0; t < 27; ++t) {
        int r = srr[t];
        if (r >= 0)
            sx[t][tid] = t1c[(size_t)r * 64 + tid];
    }
    __syncthreads();

    float acc = 0.f;
    #pragma unroll 1
    for (int t = 0; t < 27; ++t) {
        if (srr[t] < 0) continue;
        const float* wp = w1bT + (size_t)t * 4096 + tid;
        const float* xr = sx[t];
        #pragma unroll 8
        for (int ci = 0; ci < 64; ++ci)
            acc = fmaf(xr[ci], wp[ci * 64], acc);
    }
    float id = 0.f;
    #pragma unroll
    for (int ci = 0; ci < 3; ++ci)
        id = fmaf(x[(size_t)(b * 3 + ci) * 262144 + v], wdT[ci * 64 + tid], id);
    x1c[(size_t)i * 64 + tid] = leaky(acc + id);
}

// ---------------- wd1 v4: 128 threads (lane=co), packed weights ---------------
__global__ __launch_bounds__(128) void wd1_kernel(
    const float* __restrict__ x1c, const int* __restrict__ idxmap,
    const float* __restrict__ wP,   // [27][64][128] (tap, ci, co)
    ushort* __restrict__ outp)
{
    __shared__ int   srr[27];
    __shared__ float sx[27][64];
    const int tid = threadIdx.x;
    const int v = blockIdx.x;           // 0..32767
    const int b = blockIdx.y;
    const int zo = v >> 10, yo = (v >> 5) & 31, xo = v & 31;
    const int* im = idxmap + b * 262144;

    if (tid < 27) {
        int kz = tid / 9, ky = (tid / 3) % 3, kx = tid % 3;
        int zi = 2 * zo - 1 + kz, yi = 2 * yo - 1 + ky, xi = 2 * xo - 1 + kx;
        int r = -1;
        if ((unsigned)zi < 64u && (unsigned)yi < 64u && (unsigned)xi < 64u)
            r = im[(zi << 12) + (yi << 6) + xi];
        srr[tid] = r;
    }
    __syncthreads();
    #pragma unroll 1
    for (int t = 0; t < 27; ++t) {
        int r = srr[t];
        if (r >= 0 && tid < 64)
            sx[t][tid] = x1c[(size_t)r * 64 + tid];
    }
    __syncthreads();

    float acc = 0.f;
    #pragma unroll 1
    for (int t = 0; t < 27; ++t) {
        if (srr[t] < 0) continue;
        const float* wp = wP + (size_t)t * 8192 + tid;   // [t][ci][128], ci-stride 512B
        const float* xr = sx[t];
        #pragma unroll 8
        for (int ci = 0; ci < 64; ++ci)
            acc = fmaf(xr[ci], wp[ci * 128], acc);
    }
    float val = leaky(acc);
    ushort hb = f2bf(val);
    ushort lb = f2bf(val - bf2f(hb));
    size_t vb = ((((size_t)b * 32 + zo) * 32 + yo) * 33 + xo) * 256 + 256;
    int off = choff(tid);
    outp[vb + off] = hb;
    outp[vb + off + 8] = lb;
}

// ---------------- MFMA conv v6: LDS-staged B (wd2) ----------------------------
template<int CI, int CO, int DI, int DO, int STRIDE, int RY, int NX, int NCT, int WPEU, int EPI>
__global__ __launch_bounds__(256, WPEU) void mfma_conv6_kernel(
    const ushort* __restrict__ inp, const ushort* __restrict__ A,
    const float* __restrict__ mask, const ushort* __restrict__ resid,
    ushort* __restrict__ outp)
{
    constexpr int NCI = CI / 32;
    constexpr int NMT = CO / 16;
    constexpr int CV = CI * 2;
    constexpr int CVO = CO * 2;
    constexpr int YG = DO / RY;
    constexpr int NXV = (DO - 1) * STRIDE + 3;
    constexpr int LVS = (STRIDE == 2) ? 68 : 72;
    constexpr int NGRP = RY * NXV * 8;

    __shared__ ushort sB[RY * NXV * LVS];

    const int rg = (blockIdx.x & 7) * ((int)gridDim.x >> 3) + (blockIdx.x >> 3);
    const int y0 = (rg % YG) * RY;
    const int z = (rg / YG) % DO;
    const int b = rg / (YG * DO);
    const int wave = threadIdx.x >> 6;
    const int lane = threadIdx.x & 63;
    const int n_l = lane & 15;
    const int q = lane >> 4;
    const int mt0 = (blockIdx.y * 4 + wave) * NCT;

    f32x4 acc[NCT][RY][NX];
    #pragma unroll
    for (int a = 0; a < NCT; ++a)
        #pragma unroll
        for (int r = 0; r < RY; ++r)
            #pragma unroll
            for (int c = 0; c < NX; ++c)
                acc[a][r][c] = (f32x4){0.f, 0.f, 0.f, 0.f};

    #pragma unroll 1
    for (int ct = 0; ct < NCI; ++ct) {
        #pragma unroll 1
        for (int dz = 0; dz < 3; ++dz) {
            int zp = z * STRIDE + dz - 1;
            bool vz = (unsigned)zp < (unsigned)DI;
            int zpc = vz ? zp : 0;
            #pragma unroll 1
            for (int dy = 0; dy < 3; ++dy) {
                long rowb[RY];
                #pragma unroll
                for (int ry = 0; ry < RY; ++ry) {
                    int yp = (y0 + ry) * STRIDE + dy - 1;
                    bool v = vz && ((unsigned)yp < (unsigned)DI);
                    rowb[ry] = v ? (((((long)b * DI + zpc) * DI + yp) * (DI + 1)) * CV + CV) : -1;
                }
                __syncthreads();
                for (int g = threadIdx.x; g < NGRP; g += 256) {
                    int r = g / (NXV * 8);
                    int rem = g - r * (NXV * 8);
                    int xv = rem >> 3;
                    int gg = rem & 7;
                    long src = (rowb[r] >= 0)
                             ? (rowb[r] + (long)(xv - 1) * CV + ct * 64 + gg * 8)
                             : (long)(ct * 64 + gg * 8);
                    *(bf16x8*)(sB + (r * NXV + xv) * LVS + gg * 8) = *(const bf16x8*)(inp + src);
                }
                __syncthreads();
                #pragma unroll
                for (int dx = 0; dx < 3; ++dx) {
                    const int tap = dz * 9 + dy * 3 + dx;
                    bf16x8 bh[RY][NX], bl[RY][NX];
                    #pragma unroll
                    for (int ry = 0; ry < RY; ++ry)
                        #pragma unroll
                        for (int nx = 0; nx < NX; ++nx) {
                            int xv = (nx * 16 + n_l) * STRIDE + dx;
                            const ushort* p = sB + (ry * NXV + xv) * LVS + q * 16;
                            bh[ry][nx] = *(const bf16x8*)p;
                            bl[ry][nx] = *(const bf16x8*)(p + 8);
                        }
                    bf16x8 ahf[NCT], alf[NCT];
                    #pragma unroll
                    for (int mt = 0; mt < NCT; ++mt) {
                        size_t aa = ((size_t)(tap * NCI + ct) * NMT + (mt0 + mt)) * 1024 + lane * 16;
                        ahf[mt] = *(const bf16x8*)(A + aa);
                        alf[mt] = *(const bf16x8*)(A + aa + 8);
                    }
                    #pragma unroll
                    for (int mt = 0; mt < NCT; ++mt)
                        #pragma unroll
                        for (int ry = 0; ry < RY; ++ry)
                            #pragma unroll
                            for (int nx = 0; nx < NX; ++nx)
                                acc[mt][ry][nx] = __builtin_amdgcn_mfma_f32_16x16x32_bf16(ahf[mt], bh[ry][nx], acc[mt][ry][nx], 0, 0, 0);
                    #pragma unroll
                    for (int mt = 0; mt < NCT; ++mt)
                        #pragma unroll
                        for (int ry = 0; ry < RY; ++ry)
                            #pragma unroll
                            for (int nx = 0; nx < NX; ++nx)
                                acc[mt][ry][nx] = __builtin_amdgcn_mfma_f32_16x16x32_bf16(ahf[mt], bl[ry][nx], acc[mt][ry][nx], 0, 0, 0);
                    #pragma unroll
                    for (int mt = 0; mt < NCT; ++mt)
                        #pragma unroll
                        for (int ry = 0; ry < RY; ++ry)
                            #pragma unroll
                            for (int nx = 0; nx < NX; ++nx)
                                acc[mt][ry][nx] = __builtin_amdgcn_mfma_f32_16x16x32_bf16(alf[mt], bh[ry][nx], acc[mt][ry][nx], 0, 0, 0);
                }
            }
        }
    }

    #pragma unroll
    for (int ry = 0; ry < RY; ++ry) {
        int yo = y0 + ry;
        #pragma unroll
        for (int nx = 0; nx < NX; ++nx) {
            int xo = nx * 16 + n_l;
            size_t vb = ((((size_t)b * DO + z) * DO + yo) * (DO + 1)) * CVO + CVO + (size_t)xo * CVO;
            float mval = 1.f;
            if (EPI & EPI_MASK) mval = mask[(((size_t)b * DO + z) * DO + yo) * DO + xo];
            #pragma unroll
            for (int mt = 0; mt < NCT; ++mt) {
                int c0 = (mt0 + mt) * 16 + q * 4;
                size_t oa = vb + choff(c0);
                float rs[4] = {0.f, 0.f, 0.f, 0.f};
                if (EPI & EPI_RESID) {
                    us4 rh4 = *(const us4*)(resid + oa);
                    us4 rl4 = *(const us4*)(resid + oa + 8);
                    #pragma unroll
                    for (int r = 0; r < 4; ++r) rs[r] = bf2f(rh4[r]) + bf2f(rl4[r]);
                }
                us4 oh, ol;
                #pragma unroll
                for (int r = 0; r < 4; ++r) {
                    float v = acc[mt][ry][nx][r];
                    if (EPI & EPI_MASK) v *= mval;
                    if (EPI & EPI_RESID) v += rs[r];
                    if (EPI & EPI_LEAKY) v = leaky(v);
                    ushort hb = f2bf(v);
                    oh[r] = hb;
                    ol[r] = f2bf(v - bf2f(hb));
                }
                *(us4*)(outp + oa) = oh;
                *(us4*)(outp + oa + 8) = ol;
            }
        }
    }
}

// ---------------- MFMA conv v8: stage-2 convs (S=1), slab staging -------------
template<int CI, int CO, int DI, int RY, int NX, int NCT, int WPEU, int EPI>
__global__ __launch_bounds__(256, WPEU) void mfma_conv8_kernel(
    const ushort* __restrict__ inp, const ushort* __restrict__ A,
    const float* __restrict__ mask, const ushort* __restrict__ resid,
    ushort* __restrict__ outp)
{
    constexpr int DO = DI;
    constexpr int NCI = CI / 32;
    constexpr int NMT = CO / 16;
    constexpr int CV = CI * 2;
    constexpr int CVO = CO * 2;
    constexpr int YG = DO / RY;
    constexpr int NYR = RY + 2;
    constexpr int NXV = DO + 2;
    constexpr int LVS = 72;
    constexpr int NGRP = NYR * NXV * 8;

    __shared__ ushort sB[NYR * NXV * LVS];

    const int rg = (blockIdx.x & 7) * ((int)gridDim.x >> 3) + (blockIdx.x >> 3);
    const int y0 = (rg % YG) * RY;
    const int z = (rg / YG) % DO;
    const int b = rg / (YG * DO);
    const int wave = threadIdx.x >> 6;
    const int lane = threadIdx.x & 63;
    const int n_l = lane & 15;
    const int q = lane >> 4;
    const int mt0 = (blockIdx.y * 4 + wave) * NCT;

    f32x4 acc[NCT][RY][NX];
    #pragma unroll
    for (int a = 0; a < NCT; ++a)
        #pragma unroll
        for (int r = 0; r < RY; ++r)
            #pragma unroll
            for (int c = 0; c < NX; ++c)
                acc[a][r][c] = (f32x4){0.f, 0.f, 0.f, 0.f};

    #pragma unroll 1
    for (int ct = 0; ct < NCI; ++ct) {
        #pragma unroll 1
        for (int dz = 0; dz < 3; ++dz) {
            int zp = z + dz - 1;
            bool vz = (unsigned)zp < (unsigned)DI;
            int zpc = vz ? zp : 0;
            __syncthreads();
            for (int g = threadIdx.x; g < NGRP; g += 256) {
                int r = g / (NXV * 8);
                int rem = g - r * (NXV * 8);
                int xv = rem >> 3;
                int gg = rem & 7;
                int yp = y0 + r - 1;
                bool v = vz & ((unsigned)yp < (unsigned)DI);
                long src = v ? ((((((long)b * DI + zpc) * DI + yp) * (DI + 1)) * CV + CV)
                                + (long)(xv - 1) * CV + ct * 64 + gg * 8)
                             : (long)(ct * 64 + gg * 8);   // zeroed lead pad
                *(bf16x8*)(sB + (r * NXV + xv) * LVS + gg * 8) = *(const bf16x8*)(inp + src);
            }
            __syncthreads();
            #pragma unroll 1
            for (int dy = 0; dy < 3; ++dy) {
                #pragma unroll
                for (int dx = 0; dx < 3; ++dx) {
                    const int tap = dz * 9 + dy * 3 + dx;
                    bf16x8 bh[RY][NX], bl[RY][NX];
                    #pragma unroll
                    for (int ry = 0; ry < RY; ++ry)
                        #pragma unroll
                        for (int nx = 0; nx < NX; ++nx) {
                            int xv = nx * 16 + n_l + dx;
                            const ushort* p = sB + ((ry + dy) * NXV + xv) * LVS + q * 16;
                            bh[ry][nx] = *(const bf16x8*)p;
                            bl[ry][nx] = *(const bf16x8*)(p + 8);
                        }
                    bf16x8 ahf[NCT], alf[NCT];
                    #pragma unroll
                    for (int mt = 0; mt < NCT; ++mt) {
                        size_t aa = ((size_t)(tap * NCI + ct) * NMT + (mt0 + mt)) * 1024 + lane * 16;
                        ahf[mt] = *(const bf16x8*)(A + aa);
                        alf[mt] = *(const bf16x8*)(A + aa + 8);
                    }
                    #pragma unroll
                    for (int mt = 0; mt < NCT; ++mt)
                        #pragma unroll
                        for (int ry = 0; ry < RY; ++ry)
                            #pragma unroll
                            for (int nx = 0; nx < NX; ++nx)
                                acc[mt][ry][nx] = __builtin_amdgcn_mfma_f32_16x16x32_bf16(ahf[mt], bh[ry][nx], acc[mt][ry][nx], 0, 0, 0);
                    #pragma unroll
                    for (int mt = 0; mt < NCT; ++mt)
                        #pragma unroll
                        for (int ry = 0; ry < RY; ++ry)
                            #pragma unroll
                            for (int nx = 0; nx < NX; ++nx)
                                acc[mt][ry][nx] = __builtin_amdgcn_mfma_f32_16x16x32_bf16(ahf[mt], bl[ry][nx], acc[mt][ry][nx], 0, 0, 0);
                    #pragma unroll
                    for (int mt = 0; mt < NCT; ++mt)
                        #pragma unroll
                        for (int ry = 0; ry < RY; ++ry)
                            #pragma unroll
                            for (int nx = 0; nx < NX; ++nx)
                                acc[mt][ry][nx] = __builtin_amdgcn_mfma_f32_16x16x32_bf16(alf[mt], bh[ry][nx], acc[mt][ry][nx], 0, 0, 0);
                }
            }
        }
    }

    #pragma unroll
    for (int ry = 0; ry < RY; ++ry) {
        int yo = y0 + ry;
        #pragma unroll
        for (int nx = 0; nx < NX; ++nx) {
            int xo = nx * 16 + n_l;
            size_t vb = ((((size_t)b * DO + z) * DO + yo) * (DO + 1)) * CVO + CVO + (size_t)xo * CVO;
            float mval = 1.f;
            if (EPI & EPI_MASK) mval = mask[(((size_t)b * DO + z) * DO + yo) * DO + xo];
            #pragma unroll
            for (int mt = 0; mt < NCT; ++mt) {
                int c0 = (mt0 + mt) * 16 + q * 4;
                size_t oa = vb + choff(c0);
                float rs[4] = {0.f, 0.f, 0.f, 0.f};
                if (EPI & EPI_RESID) {
                    us4 rh4 = *(const us4*)(resid + oa);
                    us4 rl4 = *(const us4*)(resid + oa + 8);
                    #pragma unroll
                    for (int r = 0; r < 4; ++r) rs[r] = bf2f(rh4[r]) + bf2f(rl4[r]);
                }
                us4 oh, ol;
                #pragma unroll
                for (int r = 0; r < 4; ++r) {
                    float v = acc[mt][ry][nx][r];
                    if (EPI & EPI_MASK) v *= mval;
                    if (EPI & EPI_RESID) v += rs[r];
                    if (EPI & EPI_LEAKY) v = leaky(v);
                    ushort hb = f2bf(v);
                    oh[r] = hb;
                    ol[r] = f2bf(v - bf2f(hb));
                }
                *(us4*)(outp + oa) = oh;
                *(us4*)(outp + oa + 8) = ol;
            }
        }
    }
}

// ---------------- MFMA conv v7: stage-3 convs (S=1, DO=16), K-split ----------
template<int CI, int CO, int DI, int RY, int NCT, int KS, int WPEU>
__global__ __launch_bounds__(256, WPEU) void mfma_conv7_kernel(
    const ushort* __restrict__ inp, const ushort* __restrict__ A,
    float* __restrict__ part)
{
    constexpr int DO = DI;
    constexpr int NCI = CI / 32;
    constexpr int KCI = NCI / KS;
    constexpr int NMT = CO / 16;
    constexpr int CV = CI * 2;
    constexpr int YG = DO / RY;
    constexpr int NYR = RY + 2;
    constexpr int NXV = DO + 2;
    constexpr int LVS = 72;
    constexpr int NCOG = NMT / (4 * NCT);
    constexpr int D3 = DO * DO * DO;

    __shared__ ushort sB[3 * NYR * NXV * LVS];

    const int rg = (blockIdx.x & 7) * ((int)gridDim.x >> 3) + (blockIdx.x >> 3);
    const int y0 = (rg % YG) * RY;
    const int z = (rg / YG) % DO;
    const int b = rg / (YG * DO);
    const int wave = threadIdx.x >> 6;
    const int lane = threadIdx.x & 63;
    const int n_l = lane & 15;
    const int q = lane >> 4;
    const int cog = blockIdx.y % NCOG;
    const int kc = blockIdx.y / NCOG;
    const int mt0 = (cog * 4 + wave) * NCT;

    f32x4 acc[NCT][RY];
    #pragma unroll
    for (int a = 0; a < NCT; ++a)
        #pragma unroll
        for (int r = 0; r < RY; ++r)
            acc[a][r] = (f32x4){0.f, 0.f, 0.f, 0.f};

    #pragma unroll 1
    for (int ctl = 0; ctl < KCI; ++ctl) {
        const int ct = kc * KCI + ctl;
        __syncthreads();
        for (int g = threadIdx.x; g < 3 * NYR * NXV * 8; g += 256) {
            int row = g / (NXV * 8);
            int rem = g - row * (NXV * 8);
            int xv = rem >> 3;
            int gg = rem & 7;
            int zi = row / NYR, yr = row - zi * NYR;
            int zp = z + zi - 1;
            int yp = y0 + yr - 1;
            bool v = ((unsigned)zp < (unsigned)DI) & ((unsigned)yp < (unsigned)DI);
            long src = v ? ((((((long)b * DI + zp) * DI + yp) * (DI + 1)) * CV + CV)
                            + (long)(xv - 1) * CV + ct * 64 + gg * 8)
                         : (long)(ct * 64 + gg * 8);
            *(bf16x8*)(sB + (row * NXV + xv) * LVS + gg * 8) = *(const bf16x8*)(inp + src);
        }
        __syncthreads();
        #pragma unroll 1
        for (int dz = 0; dz < 3; ++dz) {
            #pragma unroll 1
            for (int dy = 0; dy < 3; ++dy) {
                #pragma unroll
                for (int dx = 0; dx < 3; ++dx) {
                    const int tap = dz * 9 + dy * 3 + dx;
                    bf16x8 bh[RY], bl[RY];
                    #pragma unroll
                    for (int ry = 0; ry < RY; ++ry) {
                        const ushort* p = sB + ((dz * NYR + ry + dy) * NXV + n_l + dx) * LVS + q * 16;
                        bh[ry] = *(const bf16x8*)p;
                        bl[ry] = *(const bf16x8*)(p + 8);
                    }
                    bf16x8 ahf[NCT], alf[NCT];
                    #pragma unroll
                    for (int mt = 0; mt < NCT; ++mt) {
                        size_t aa = ((size_t)(tap * NCI + ct) * NMT + (mt0 + mt)) * 1024 + lane * 16;
                        ahf[mt] = *(const bf16x8*)(A + aa);
                        alf[mt] = *(const bf16x8*)(A + aa + 8);
                    }
                    #pragma unroll
                    for (int mt = 0; mt < NCT; ++mt)
                        #pragma unroll
                        for (int ry = 0; ry < RY; ++ry)
                            acc[mt][ry] = __builtin_amdgcn_mfma_f32_16x16x32_bf16(ahf[mt], bh[ry], acc[mt][ry], 0, 0, 0);
                    #pragma unroll
                    for (int mt = 0; mt < NCT; ++mt)
                        #pragma unroll
                        for (int ry = 0; ry < RY; ++ry)
                            acc[mt][ry] = __builtin_amdgcn_mfma_f32_16x16x32_bf16(ahf[mt], bl[ry], acc[mt][ry], 0, 0, 0);
                    #pragma unroll
                    for (int mt = 0; mt < NCT; ++mt)
                        #pragma unroll
                        for (int ry = 0; ry < RY; ++ry)
                            acc[mt][ry] = __builtin_amdgcn_mfma_f32_16x16x32_bf16(alf[mt], bh[ry], acc[mt][ry], 0, 0, 0);
                }
            }
        }
    }

    #pragma unroll
    for (int ry = 0; ry < RY; ++ry) {
        int yo = y0 + ry;
        int v = (z * DO + yo) * DO + n_l;
        #pragma unroll
        for (int mt = 0; mt < NCT; ++mt) {
            int c0 = (mt0 + mt) * 16 + q * 4;
            size_t off = (((size_t)kc * 2 + b) * D3 + v) * CO + c0;
            *(f32x4*)(part + off) = acc[mt][ry];
        }
    }
}

// ---------------- combine3: sum K-split halves + epilogue -> interleaved CL ---
__global__ __launch_bounds__(256) void combine3_kernel(
    const float* __restrict__ part, const float* __restrict__ mask,
    const ushort* __restrict__ resid, ushort* __restrict__ outp)
{
    int i = blockIdx.x * 256 + threadIdx.x;      // over 2*4096*64
    if (i >= 2 * 4096 * 64) return;
    int g = i & 63, v = (i >> 6) & 4095, b = i >> 18;
    int c0 = g * 4;
    size_t p0 = (((size_t)b) * 4096 + v) * 256 + c0;
    float4 s0 = *(const float4*)(part + p0);
    float4 s1 = *(const float4*)(part + p0 + (size_t)2 * 4096 * 256);
    float m = mask[b * 4096 + v];
    int z = v >> 8, y = (v >> 4) & 15, x = v & 15;
    size_t vb = ((((size_t)b * 16 + z) * 16 + y) * 17) * 512 + 512 + (size_t)x * 512;
    size_t oa = vb + choff(c0);
    float rs[4] = {0.f, 0.f, 0.f, 0.f};
    if (resid) {
        us4 rh = *(const us4*)(resid + oa);
        us4 rl = *(const us4*)(resid + oa + 8);
        #pragma unroll
        for (int r = 0; r < 4; ++r) rs[r] = bf2f(rh[r]) + bf2f(rl[r]);
    }
    float sv[4] = {s0.x + s1.x, s0.y + s1.y, s0.z + s1.z, s0.w + s1.w};
    us4 oh, ol;
    #pragma unroll
    for (int r = 0; r < 4; ++r) {
        float val = sv[r] * m + rs[r];
        val = leaky(val);
        ushort hb = f2bf(val);
        oh[r] = hb;
        ol[r] = f2bf(val - bf2f(hb));
    }
    *(us4*)(outp + oa) = oh;
    *(us4*)(outp + oa + 8) = ol;
}

// ---------------- wd3 via MFMA (product-major) -> x4 fp32 ---------------------
__global__ __launch_bounds__(256) void wd3_mfma_kernel(
    const ushort* __restrict__ x3, const ushort* __restrict__ A,
    float* __restrict__ x4)
{
    constexpr int NCI = 8;   // 256/32
    constexpr int NMT = 8;   // 128/16
    const int blk = blockIdx.x;
    const int yg = blk & 3;
    const int z = (blk >> 2) & 7;
    const int b = blk >> 5;
    const int wave = threadIdx.x >> 6;
    const int lane = threadIdx.x & 63;
    const int n_l = lane & 15;
    const int q = lane >> 4;
    const int y = yg * 2 + (n_l >> 3);
    const int x = n_l & 7;
    const int mt0 = wave * 2;

    f32x4 acc[2];
    acc[0] = (f32x4){0.f, 0.f, 0.f, 0.f};
    acc[1] = (f32x4){0.f, 0.f, 0.f, 0.f};
    const bf16x8 zero8 = {0, 0, 0, 0, 0, 0, 0, 0};

    for (int ct = 0; ct < NCI; ++ct) {
        #pragma unroll
        for (int dz = 0; dz < 3; ++dz) {
            int zp = 2 * z + dz - 1;
            if ((unsigned)zp >= 16u) continue;
            #pragma unroll
            for (int dy = 0; dy < 3; ++dy) {
                int yp = 2 * y + dy - 1;
                bool vy = (unsigned)yp < 16u;
                int ypc = vy ? yp : 0;
                #pragma unroll
                for (int dx = 0; dx < 3; ++dx) {
                    int xp = 2 * x + dx - 1;
                    int tap = dz * 9 + dy * 3 + dx;
                    size_t ba = ((((size_t)b * 16 + zp) * 16 + ypc) * 17 + 1 + xp) * 512
                              + ct * 64 + q * 16;
                    bf16x8 bh = vy ? *(const bf16x8*)(x3 + ba) : zero8;
                    bf16x8 bl = vy ? *(const bf16x8*)(x3 + ba + 8) : zero8;
                    bf16x8 ahf[2], alf[2];
                    #pragma unroll
                    for (int mt = 0; mt < 2; ++mt) {
                        size_t aa = ((size_t)(tap * NCI + ct) * NMT + (mt0 + mt)) * 1024 + lane * 16;
                        ahf[mt] = *(const bf16x8*)(A + aa);
                        alf[mt] = *(const bf16x8*)(A + aa + 8);
                    }
                    #pragma unroll
                    for (int mt = 0; mt < 2; ++mt)
                        acc[mt] = __builtin_amdgcn_mfma_f32_16x16x32_bf16(ahf[mt], bh, acc[mt], 0, 0, 0);
                    #pragma unroll
                    for (int mt = 0; mt < 2; ++mt)
                        acc[mt] = __builtin_amdgcn_mfma_f32_16x16x32_bf16(ahf[mt], bl, acc[mt], 0, 0, 0);
                    #pragma unroll
                    for (int mt = 0; mt < 2; ++mt)
                        acc[mt] = __builtin_amdgcn_mfma_f32_16x16x32_bf16(alf[mt], bh, acc[mt], 0, 0, 0);
                }
            }
        }
    }
    #pragma unroll
    for (int mt = 0; mt < 2; ++mt)
        #pragma unroll
        for (int r = 0; r < 4; ++r) {
            int co = (mt0 + mt) * 16 + q * 4 + r;
            x4[((size_t)(b * 128 + co)) * 512 + z * 64 + y * 8 + x] = leaky(acc[mt][r]);
        }
}

// ---------------- final: mean/max pool over 8^3 -------------------------------
__global__ __launch_bounds__(64) void reduce_kernel(
    const float* __restrict__ x4, float* __restrict__ out)
{
    int bc = blockIdx.x;
    int b = bc >> 7, c = bc & 127;
    const float* p = x4 + (size_t)(b * 128 + c) * 512;
    float s = 0.f, mx = -3.4e38f;
    for (int i = threadIdx.x; i < 512; i += 64) {
        float v = p[i];
        s += v;
        mx = fmaxf(mx, v);
    }
    #pragma unroll
    for (int o = 32; o > 0; o >>= 1) {
        s += __shfl_down(s, o);
        mx = fmaxf(mx, __shfl_down(mx, o));
    }
    if (threadIdx.x == 0) {
        out[b * 256 + c] = s * (1.f / 512.f);
        out[b * 256 + 128 + c] = mx;
    }
}

__global__ __launch_bounds__(256) void zero_out_kernel(float* __restrict__ out, int n)
{
    int i = blockIdx.x * 256 + threadIdx.x;
    if (i < n) out[i] = 0.f;
}

// ---------------------------------------------------------------------------
extern "C" void kernel_launch(void* const* d_in, const int* in_sizes, int n_in,
                              void* d_out, int out_size, void* d_ws, size_t ws_size,
                              hipStream_t stream)
{
    (void)in_sizes; (void)n_in;
    const float* x    = (const float*)d_in[0];
    const float* mask = (const float*)d_in[1];
    const float* w1a  = (const float*)d_in[2];
    const float* w1b  = (const float*)d_in[3];
    const float* w1d  = (const float*)d_in[4];
    const float* wd1  = (const float*)d_in[5];
    const float* w2a  = (const float*)d_in[6];
    const float* w2b  = (const float*)d_in[7];
    const float* wd2  = (const float*)d_in[8];
    const float* w3a  = (const float*)d_in[9];
    const float* w3b  = (const float*)d_in[10];
    const float* wd3  = (const float*)d_in[11];
    float* out = (float*)d_out;
    char* ws = (char*)d_ws;

    const size_t RSZ = 34603520;      // stage-2 tensor region (interleaved)
    const size_t SZ3 = 8913920;       // stage-3 tensor bytes
    const size_t POFF = 9437184;      // partial-buffer offset within R2/R3
    char* R1 = ws;
    char* R2 = ws + RSZ;
    char* R3 = ws + 2 * RSZ;
    size_t off = 3 * RSZ;
    auto alloc = [&](size_t bytes) { char* p = ws + off; off = (off + bytes + 255) & ~255ull; return p; };
    ushort* pk2a = (ushort*)alloc(1769472);
    ushort* pk2b = (ushort*)alloc(1769472);
    ushort* pkd2 = (ushort*)alloc(3538944);
    ushort* pk3a = (ushort*)alloc(7077888);
    ushort* pk3b = (ushort*)alloc(7077888);
    float*  wd1P = (float*)alloc(884736);
    float*  waT  = (float*)alloc(20736);
    float*  w1bT = (float*)alloc(442368);
    float*  wdTt = (float*)alloc(768);
    float*  m2   = (float*)alloc(262144);
    float*  m3   = (float*)alloc(32768);
    int*    cnt  = (int*)alloc(256);
    const size_t NEED = off;

    if (ws_size < NEED) {
        zero_out_kernel<<<dim3((out_size + 255) / 256), 256, 0, stream>>>(out, out_size);
        return;
    }

    // stage-1 scratch aliased into R2 (dead before t2 is written)
    float* t1c  = (float*)R2;
    float* x1c  = (float*)(R2 + 8388608);
    int*   idx  = (int*)(R2 + 16777216);
    int*   list = (int*)(R2 + 18874368);
    // late-phase aliases
    ushort* pkd3 = (ushort*)R1;       // xin3 dead after conv3b combine
    float*  x4   = (float*)R2;        // t3 dead after conv3b conv
    float*  part3a = (float*)(R2 + POFF);
    float*  part3b = (float*)(R3 + POFF);

    ushort* xin2 = (ushort*)R1;
    ushort* t2   = (ushort*)R2;
    ushort* x2   = (ushort*)R3;
    ushort* xin3 = (ushort*)R1;
    ushort* t3   = (ushort*)R2;
    ushort* x3   = (ushort*)R3;

    hipMemsetAsync(cnt, 0, 4, stream);
    hipMemsetAsync(idx, 0xFF, 2097152, stream);
    hipMemsetAsync(R1, 0, RSZ, stream);           // xin2 pads

    auto tg = [](int n) { return dim3((n + 255) / 256); };
    pack_w_kernel<<<tg(27 * 128 * 128 * 2), 256, 0, stream>>>(w2a, pk2a, 128, 128);
    pack_w_kernel<<<tg(27 * 128 * 128 * 2), 256, 0, stream>>>(w2b, pk2b, 128, 128);
    pack_w_kernel<<<tg(27 * 128 * 256 * 2), 256, 0, stream>>>(wd2, pkd2, 128, 256);
    pack_w_kernel<<<tg(27 * 256 * 256 * 2), 256, 0, stream>>>(w3a, pk3a, 256, 256);
    pack_w_kernel<<<tg(27 * 256 * 256 * 2), 256, 0, stream>>>(w3b, pk3b, 256, 256);
    pack_wd1_kernel    <<<tg(27 * 64 * 128), 256, 0, stream>>>(wd1, wd1P);
    transpose_w_kernel <<<tg(64 * 81),    256, 0, stream>>>(w1a, waT,  64, 81);
    pack_w1b_kernel    <<<tg(27 * 64 * 64), 256, 0, stream>>>(w1b, w1bT);
    transpose_w_kernel <<<tg(64 * 3),     256, 0, stream>>>(w1d, wdTt, 64, 3);

    maxpool_kernel<64, 32><<<dim3(2 * 32768 / 256), 256, 0, stream>>>(mask, m2);
    maxpool_kernel<32, 16><<<dim3(2 * 4096 / 256),  256, 0, stream>>>(m2, m3);
    build_list_kernel<<<dim3(2 * 262144 / 256), 256, 0, stream>>>(mask, list, idx, cnt);

    // stage 1 (sparse, fp32)
    stage1a_kernel<<<dim3(2048), 64, 0, stream>>>(x, waT, list, cnt, t1c);
    stage1b_kernel<<<dim3(ROWCAP), 64, 0, stream>>>(t1c, x, w1bT, wdTt, list, idx, cnt, x1c);
    wd1_kernel<<<dim3(32768, 2), 128, 0, stream>>>(x1c, idx, wd1P, xin2);

    // stage-1 scratch dead; clear R2/R3 (t2/x2 pads)
    hipMemsetAsync(R2, 0, RSZ, stream);
    hipMemsetAsync(R3, 0, RSZ, stream);

    // stage2 res block: conv8 slab staging (RY=2/NX=2/NCT=2, 1024 blocks)
    mfma_conv8_kernel<128, 128, 32, 2, 2, 2, 4, EPI_MASK | EPI_LEAKY>
        <<<dim3(1024, 1), 256, 0, stream>>>(xin2, pk2a, m2, nullptr, t2);
    mfma_conv8_kernel<128, 128, 32, 2, 2, 2, 4, EPI_MASK | EPI_RESID | EPI_LEAKY>
        <<<dim3(1024, 1), 256, 0, stream>>>(t2, pk2b, m2, xin2, x2);

    // xin2 dead -> clear xin3 area; wd2 (conv6)
    hipMemsetAsync(R1, 0, SZ3, stream);
    mfma_conv6_kernel<128, 256, 32, 16, 2, 2, 1, 2, 4, EPI_LEAKY>
        <<<dim3(256, 2), 256, 0, stream>>>(x2, pkd2, nullptr, nullptr, xin3);

    // conv3a: conv7 (K-split) -> partials; combine -> t3
    hipMemsetAsync(R2, 0, SZ3, stream);
    mfma_conv7_kernel<256, 256, 16, 2, 2, 2, 4>
        <<<dim3(256, 4), 256, 0, stream>>>(xin3, pk3a, part3a);
    combine3_kernel<<<dim3(2048), 256, 0, stream>>>(part3a, m3, nullptr, t3);

    // conv3b: conv7 -> partials; combine (resid=xin3) -> x3
    hipMemsetAsync(R3, 0, SZ3, stream);
    mfma_conv7_kernel<256, 256, 16, 2, 2, 2, 4>
        <<<dim3(256, 4), 256, 0, stream>>>(t3, pk3b, part3b);
    combine3_kernel<<<dim3(2048), 256, 0, stream>>>(part3b, m3, xin3, x3);

    // xin3 (R1) and t3 (R2) dead: pack wd3 -> R1, MFMA wd3 -> x4 (R2)
    pack_w_kernel<<<tg(27 * 256 * 128 * 2), 256, 0, stream>>>(wd3, pkd3, 256, 128);
    wd3_mfma_kernel<<<dim3(64), 256, 0, stream>>>(x3, pkd3, x4);

    reduce_kernel<<<dim3(256), 64, 0, stream>>>(x4, out);
}

// Round 21
// 1066.656 us; speedup vs baseline: 1.0987x; 1.0505x over previous
//
#include <hip/hip_runtime.h>

// ---------------------------------------------------------------------------
// SparseEncoderResUNet on MI355X — round 21: pad-only zeroing + ballot taps.
// r20: 1121us, flat profile, wd1 152us top. Two wastes removed:
//  (a) ~130MB of full-region memsets replaced by pad-slot zeroing (~4MB):
//      every interior voxel is densely overwritten by its producer; only
//      per-row halo slot 0 (+trailing slot) must be zero.
//  (b) wd1/stage1b: ballot mask of active taps + __ffsll iteration visits
//      only ~1.35 active taps (ascending order -> bit-identical) instead of
//      27 conditional iterations.
// Everything else frozen from r20.
// ---------------------------------------------------------------------------

enum { EPI_MASK = 1, EPI_LEAKY = 2, EPI_RESID = 4 };
#define ROWCAP 32768

typedef short  bf16x8 __attribute__((ext_vector_type(8)));
typedef float  f32x4  __attribute__((ext_vector_type(4)));
typedef ushort us4    __attribute__((ext_vector_type(4)));

__device__ __forceinline__ float leaky(float v) { return v >= 0.f ? v : 0.2f * v; }
__device__ __forceinline__ ushort f2bf(float f) {
    unsigned u = __float_as_uint(f);
    return (ushort)((u + 0x7FFFu + ((u >> 16) & 1u)) >> 16);
}
__device__ __forceinline__ float bf2f(ushort h) {
    return __uint_as_float((unsigned)h << 16);
}
// channel c -> offset within a voxel's CI*2 block (interleaved hi/lo by 8)
__device__ __forceinline__ int choff(int c) {
    return (c >> 5) * 64 + ((c >> 3) & 3) * 16 + (c & 7);
}

// ---------------- pad-slot zeroing: slots r*slotstride, r in [0, nrows] ------
// slotsize/slotstride in ushorts; writes 8 ushorts (16B) per thread.
__global__ __launch_bounds__(256) void pad_zero_kernel(
    ushort* __restrict__ base, int nrows, int slotstride, int slotsize)
{
    int i = blockIdx.x * 256 + threadIdx.x;
    int per = slotsize >> 3;
    int total = (nrows + 1) * per;
    if (i >= total) return;
    int slot = i / per, w = i - slot * per;
    *(uint4*)(base + (size_t)slot * slotstride + w * 8) = make_uint4(0, 0, 0, 0);
}

// ---------------- weight transpose: w[co][cik] -> wT[cik][co] ----------------
__global__ __launch_bounds__(256) void transpose_w_kernel(
    const float* __restrict__ w, float* __restrict__ wT, int CO, int CIK)
{
    int i = blockIdx.x * 256 + threadIdx.x;
    if (i >= CO * CIK) return;
    int co = i / CIK, r = i - co * CIK;
    wT[(size_t)r * CO + co] = w[i];
}

// stage1b tap-major weights: w1bT[t][ci][co] = w1b[co][ci][t]
__global__ __launch_bounds__(256) void pack_w1b_kernel(
    const float* __restrict__ w, float* __restrict__ wT)
{
    int i = blockIdx.x * 256 + threadIdx.x;
    if (i >= 27 * 64 * 64) return;
    int co = i & 63, ci = (i >> 6) & 63, t = i >> 12;
    wT[i] = w[(co * 64 + ci) * 27 + t];
}

// wd1 tap-major weights: wd1P[t][ci][co] = wd1[co][ci][t]  (co=128, ci=64)
__global__ __launch_bounds__(256) void pack_wd1_kernel(
    const float* __restrict__ w, float* __restrict__ wP)
{
    int i = blockIdx.x * 256 + threadIdx.x;
    if (i >= 27 * 64 * 128) return;
    int co = i & 127, ci = (i >> 7) & 63, t = i >> 13;
    wP[i] = w[(co * 64 + ci) * 27 + t];
}

// ---------------- pack weights into MFMA A-frag layout, hi/lo interleaved ----
__global__ __launch_bounds__(256) void pack_w_kernel(
    const float* __restrict__ w, ushort* __restrict__ A, int CI, int CO)
{
    int i = blockIdx.x * 256 + threadIdx.x;
    if (i >= 27 * CI * CO * 2) return;
    int j = i & 7, hilo = (i >> 3) & 1, L = (i >> 4) & 63, rest = i >> 10;
    int NMT = CO >> 4, NCI = CI >> 5;
    int mt = rest % NMT; rest /= NMT;
    int ct = rest % NCI;
    int tap = rest / NCI;
    int co = mt * 16 + (L & 15);
    int ci = ct * 32 + (L >> 4) * 8 + j;
    float v = w[((size_t)co * CI + ci) * 27 + tap];
    ushort h = f2bf(v);
    A[i] = hilo ? f2bf(v - bf2f(h)) : h;
}

// ---------------- maxpool k3 s2 p1 (down_mask) ----------------
template<int DIN, int DOUT>
__global__ __launch_bounds__(256) void maxpool_kernel(
    const float* __restrict__ in, float* __restrict__ out)
{
    int i = blockIdx.x * 256 + threadIdx.x;
    constexpr int D3O = DOUT * DOUT * DOUT;
    if (i >= 2 * D3O) return;
    int b = i / D3O;
    int v = i - b * D3O;
    int z = v / (DOUT * DOUT), y = (v / DOUT) % DOUT, x = v % DOUT;
    float mx = 0.f;
    #pragma unroll
    for (int dz = 0; dz < 3; ++dz)
        #pragma unroll
        for (int dy = 0; dy < 3; ++dy)
            #pragma unroll
            for (int dx = 0; dx < 3; ++dx) {
                int zi = 2 * z - 1 + dz, yi = 2 * y - 1 + dy, xi = 2 * x - 1 + dx;
                if ((unsigned)zi < (unsigned)DIN && (unsigned)yi < (unsigned)DIN &&
                    (unsigned)xi < (unsigned)DIN)
                    mx = fmaxf(mx, in[(size_t)b * DIN * DIN * DIN + (zi * DIN + yi) * DIN + xi]);
            }
    out[i] = mx;
}

// ---------------- active-voxel list + dense index map ----------------
__global__ __launch_bounds__(256) void build_list_kernel(
    const float* __restrict__ m, int* __restrict__ list, int* __restrict__ idxmap,
    int* __restrict__ count)
{
    int i = blockIdx.x * 256 + threadIdx.x;
    if (i >= 2 * 262144) return;
    if (m[i] > 0.5f) {
        int k = atomicAdd(count, 1);
        if (k < ROWCAP) {
            list[k] = i;
            idxmap[i] = k;
        }
    }
}

// ---------------- stage1 conv-a (3->64, gathered) -> t1c[row][64] ----------------
__global__ __launch_bounds__(64) void stage1a_kernel(
    const float* __restrict__ x, const float* __restrict__ waT,
    const int* __restrict__ list, const int* __restrict__ count,
    float* __restrict__ t1c)
{
    __shared__ float smem[81];
    int n = min(*count, ROWCAP);
    for (int i = blockIdx.x; i < n; i += gridDim.x) {
        int lin = list[i];
        int b = lin >> 18;
        int v = lin & 262143;
        int z = v >> 12, y = (v >> 6) & 63, xx = v & 63;
        for (int j = threadIdx.x; j < 81; j += 64) {
            int ci = j / 27, t = j - ci * 27;
            int zz = z + t / 9 - 1, yy = y + (t / 3) % 3 - 1, xc = xx + t % 3 - 1;
            float val = 0.f;
            if ((unsigned)zz < 64u && (unsigned)yy < 64u && (unsigned)xc < 64u)
                val = x[(size_t)(b * 3 + ci) * 262144 + (zz << 12) + (yy << 6) + xc];
            smem[j] = val;
        }
        __syncthreads();
        float acc = 0.f;
        #pragma unroll 9
        for (int j = 0; j < 81; ++j)
            acc = fmaf(smem[j], waT[j * 64 + threadIdx.x], acc);
        t1c[(size_t)i * 64 + threadIdx.x] = leaky(acc);
        __syncthreads();
    }
}

// ---------------- stage1 conv-b v3: ballot-compacted sparse taps --------------
__global__ __launch_bounds__(64) void stage1b_kernel(
    const float* __restrict__ t1c, const float* __restrict__ x,
    const float* __restrict__ w1bT,  // [27][64][64] (tap, ci, co)
    const float* __restrict__ wdT,   // [3][64]
    const int* __restrict__ list, const int* __restrict__ idxmap,
    const int* __restrict__ count,
    float* __restrict__ x1c)
{
    __shared__ int   srr[27];
    __shared__ float sx[27][64];
    int n = min(*count, ROWCAP);
    int i = blockIdx.x;
    if (i >= n) return;
    const int tid = threadIdx.x;
    int lin = list[i];
    int b = lin >> 18;
    int v = lin & 262143;
    int z = v >> 12, y = (v >> 6) & 63, xx = v & 63;
    const int* im = idxmap + b * 262144;

    int r = -1;
    if (tid < 27) {
        int kz = tid / 9, ky = (tid / 3) % 3, kx = tid % 3;
        int zz = z + kz - 1, yy = y + ky - 1, xc = xx + kx - 1;
        if ((unsigned)zz < 64u && (unsigned)yy < 64u && (unsigned)xc < 64u)
            r = im[(zz << 12) + (yy << 6) + xc];
        srr[tid] = r;
    }
    unsigned long long mask = __ballot(r >= 0);   // single wave: all lanes agree
    __syncthreads();
    unsigned long long mm = mask;
    while (mm) {
        int t = __ffsll((unsigned long long)mm) - 1;
        mm &= mm - 1;
        sx[t][tid] = t1c[(size_t)srr[t] * 64 + tid];
    }
    __syncthreads();

    float acc = 0.f;
    mm = mask;
    while (mm) {
        int t = __ffsll((unsigned long long)mm) - 1;
        mm &= mm - 1;
        const float* wp = w1bT + (size_t)t * 4096 + tid;
        const float* xr = sx[t];
        #pragma unroll 8
        for (int ci = 0; ci < 64; ++ci)
            acc = fmaf(xr[ci], wp[ci * 64], acc);
    }
    float id = 0.f;
    #pragma unroll
    for (int ci = 0; ci < 3; ++ci)
        id = fmaf(x[(size_t)(b * 3 + ci) * 262144 + v], wdT[ci * 64 + tid], id);
    x1c[(size_t)i * 64 + tid] = leaky(acc + id);
}

// ---------------- wd1 v5: 128 threads, packed weights, ballot taps ------------
__global__ __launch_bounds__(128) void wd1_kernel(
    const float* __restrict__ x1c, const int* __restrict__ idxmap,
    const float* __restrict__ wP,   // [27][64][128] (tap, ci, co)
    ushort* __restrict__ outp)
{
    __shared__ int   srr[27];
    __shared__ unsigned long long smask;
    __shared__ float sx[27][64];
    const int tid = threadIdx.x;
    const int v = blockIdx.x;           // 0..32767
    const int b = blockIdx.y;
    const int zo = v >> 10, yo = (v >> 5) & 31, xo = v & 31;
    const int* im = idxmap + b * 262144;

    int r = -1;
    if (tid < 27) {
        int kz = tid / 9, ky = (tid / 3) % 3, kx = tid % 3;
        int zi = 2 * zo - 1 + kz, yi = 2 * yo - 1 + ky, xi = 2 * xo - 1 + kx;
        if ((unsigned)zi < 64u && (unsigned)yi < 64u && (unsigned)xi < 64u)
            r = im[(zi << 12) + (yi << 6) + xi];
        srr[tid] = r;
    }
    if (tid < 64) {                      // wave 0 computes the mask
        unsigned long long m0 = __ballot(r >= 0);
        if (tid == 0) smask = m0;
    }
    __syncthreads();
    const unsigned long long mask = smask;

    unsigned long long mm = mask;
    while (mm) {
        int t = __ffsll((unsigned long long)mm) - 1;
        mm &= mm - 1;
        if (tid < 64)
            sx[t][tid] = x1c[(size_t)srr[t] * 64 + tid];
    }
    __syncthreads();

    float acc = 0.f;
    mm = mask;
    while (mm) {
        int t = __ffsll((unsigned long long)mm) - 1;
        mm &= mm - 1;
        const float* wp = wP + (size_t)t * 8192 + tid;   // ci-stride 512B
        const float* xr = sx[t];
        #pragma unroll 8
        for (int ci = 0; ci < 64; ++ci)
            acc = fmaf(xr[ci], wp[ci * 128], acc);
    }
    float val = leaky(acc);
    ushort hb = f2bf(val);
    ushort lb = f2bf(val - bf2f(hb));
    size_t vb = ((((size_t)b * 32 + zo) * 32 + yo) * 33 + xo) * 256 + 256;
    int off = choff(tid);
    outp[vb + off] = hb;
    outp[vb + off + 8] = lb;
}

// ---------------- MFMA conv v6: LDS-staged B (wd2) ----------------------------
template<int CI, int CO, int DI, int DO, int STRIDE, int RY, int NX, int NCT, int WPEU, int EPI>
__global__ __launch_bounds__(256, WPEU) void mfma_conv6_kernel(
    const ushort* __restrict__ inp, const ushort* __restrict__ A,
    const float* __restrict__ mask, const ushort* __restrict__ resid,
    ushort* __restrict__ outp)
{
    constexpr int NCI = CI / 32;
    constexpr int NMT = CO / 16;
    constexpr int CV = CI * 2;
    constexpr int CVO = CO * 2;
    constexpr int YG = DO / RY;
    constexpr int NXV = (DO - 1) * STRIDE + 3;
    constexpr int LVS = (STRIDE == 2) ? 68 : 72;
    constexpr int NGRP = RY * NXV * 8;

    __shared__ ushort sB[RY * NXV * LVS];

    const int rg = (blockIdx.x & 7) * ((int)gridDim.x >> 3) + (blockIdx.x >> 3);
    const int y0 = (rg % YG) * RY;
    const int z = (rg / YG) % DO;
    const int b = rg / (YG * DO);
    const int wave = threadIdx.x >> 6;
    const int lane = threadIdx.x & 63;
    const int n_l = lane & 15;
    const int q = lane >> 4;
    const int mt0 = (blockIdx.y * 4 + wave) * NCT;

    f32x4 acc[NCT][RY][NX];
    #pragma unroll
    for (int a = 0; a < NCT; ++a)
        #pragma unroll
        for (int r = 0; r < RY; ++r)
            #pragma unroll
            for (int c = 0; c < NX; ++c)
                acc[a][r][c] = (f32x4){0.f, 0.f, 0.f, 0.f};

    #pragma unroll 1
    for (int ct = 0; ct < NCI; ++ct) {
        #pragma unroll 1
        for (int dz = 0; dz < 3; ++dz) {
            int zp = z * STRIDE + dz - 1;
            bool vz = (unsigned)zp < (unsigned)DI;
            int zpc = vz ? zp : 0;
            #pragma unroll 1
            for (int dy = 0; dy < 3; ++dy) {
                long rowb[RY];
                #pragma unroll
                for (int ry = 0; ry < RY; ++ry) {
                    int yp = (y0 + ry) * STRIDE + dy - 1;
                    bool v = vz && ((unsigned)yp < (unsigned)DI);
                    rowb[ry] = v ? (((((long)b * DI + zpc) * DI + yp) * (DI + 1)) * CV + CV) : -1;
                }
                __syncthreads();
                for (int g = threadIdx.x; g < NGRP; g += 256) {
                    int r = g / (NXV * 8);
                    int rem = g - r * (NXV * 8);
                    int xv = rem >> 3;
                    int gg = rem & 7;
                    long src = (rowb[r] >= 0)
                             ? (rowb[r] + (long)(xv - 1) * CV + ct * 64 + gg * 8)
                             : (long)(ct * 64 + gg * 8);
                    *(bf16x8*)(sB + (r * NXV + xv) * LVS + gg * 8) = *(const bf16x8*)(inp + src);
                }
                __syncthreads();
                #pragma unroll
                for (int dx = 0; dx < 3; ++dx) {
                    const int tap = dz * 9 + dy * 3 + dx;
                    bf16x8 bh[RY][NX], bl[RY][NX];
                    #pragma unroll
                    for (int ry = 0; ry < RY; ++ry)
                        #pragma unroll
                        for (int nx = 0; nx < NX; ++nx) {
                            int xv = (nx * 16 + n_l) * STRIDE + dx;
                            const ushort* p = sB + (ry * NXV + xv) * LVS + q * 16;
                            bh[ry][nx] = *(const bf16x8*)p;
                            bl[ry][nx] = *(const bf16x8*)(p + 8);
                        }
                    bf16x8 ahf[NCT], alf[NCT];
                    #pragma unroll
                    for (int mt = 0; mt < NCT; ++mt) {
                        size_t aa = ((size_t)(tap * NCI + ct) * NMT + (mt0 + mt)) * 1024 + lane * 16;
                        ahf[mt] = *(const bf16x8*)(A + aa);
                        alf[mt] = *(const bf16x8*)(A + aa + 8);
                    }
                    #pragma unroll
                    for (int mt = 0; mt < NCT; ++mt)
                        #pragma unroll
                        for (int ry = 0; ry < RY; ++ry)
                            #pragma unroll
                            for (int nx = 0; nx < NX; ++nx)
                                acc[mt][ry][nx] = __builtin_amdgcn_mfma_f32_16x16x32_bf16(ahf[mt], bh[ry][nx], acc[mt][ry][nx], 0, 0, 0);
                    #pragma unroll
                    for (int mt = 0; mt < NCT; ++mt)
                        #pragma unroll
                        for (int ry = 0; ry < RY; ++ry)
                            #pragma unroll
                            for (int nx = 0; nx < NX; ++nx)
                                acc[mt][ry][nx] = __builtin_amdgcn_mfma_f32_16x16x32_bf16(ahf[mt], bl[ry][nx], acc[mt][ry][nx], 0, 0, 0);
                    #pragma unroll
                    for (int mt = 0; mt < NCT; ++mt)
                        #pragma unroll
                        for (int ry = 0; ry < RY; ++ry)
                            #pragma unroll
                            for (int nx = 0; nx < NX; ++nx)
                                acc[mt][ry][nx] = __builtin_amdgcn_mfma_f32_16x16x32_bf16(alf[mt], bh[ry][nx], acc[mt][ry][nx], 0, 0, 0);
                }
            }
        }
    }

    #pragma unroll
    for (int ry = 0; ry < RY; ++ry) {
        int yo = y0 + ry;
        #pragma unroll
        for (int nx = 0; nx < NX; ++nx) {
            int xo = nx * 16 + n_l;
            size_t vb = ((((size_t)b * DO + z) * DO + yo) * (DO + 1)) * CVO + CVO + (size_t)xo * CVO;
            float mval = 1.f;
            if (EPI & EPI_MASK) mval = mask[(((size_t)b * DO + z) * DO + yo) * DO + xo];
            #pragma unroll
            for (int mt = 0; mt < NCT; ++mt) {
                int c0 = (mt0 + mt) * 16 + q * 4;
                size_t oa = vb + choff(c0);
                float rs[4] = {0.f, 0.f, 0.f, 0.f};
                if (EPI & EPI_RESID) {
                    us4 rh4 = *(const us4*)(resid + oa);
                    us4 rl4 = *(const us4*)(resid + oa + 8);
                    #pragma unroll
                    for (int r = 0; r < 4; ++r) rs[r] = bf2f(rh4[r]) + bf2f(rl4[r]);
                }
                us4 oh, ol;
                #pragma unroll
                for (int r = 0; r < 4; ++r) {
                    float v = acc[mt][ry][nx][r];
                    if (EPI & EPI_MASK) v *= mval;
                    if (EPI & EPI_RESID) v += rs[r];
                    if (EPI & EPI_LEAKY) v = leaky(v);
                    ushort hb = f2bf(v);
                    oh[r] = hb;
                    ol[r] = f2bf(v - bf2f(hb));
                }
                *(us4*)(outp + oa) = oh;
                *(us4*)(outp + oa + 8) = ol;
            }
        }
    }
}

// ---------------- MFMA conv v8: stage-2 convs (S=1), slab staging -------------
template<int CI, int CO, int DI, int RY, int NX, int NCT, int WPEU, int EPI>
__global__ __launch_bounds__(256, WPEU) void mfma_conv8_kernel(
    const ushort* __restrict__ inp, const ushort* __restrict__ A,
    const float* __restrict__ mask, const ushort* __restrict__ resid,
    ushort* __restrict__ outp)
{
    constexpr int DO = DI;
    constexpr int NCI = CI / 32;
    constexpr int NMT = CO / 16;
    constexpr int CV = CI * 2;
    constexpr int CVO = CO * 2;
    constexpr int YG = DO / RY;
    constexpr int NYR = RY + 2;
    constexpr int NXV = DO + 2;
    constexpr int LVS = 72;
    constexpr int NGRP = NYR * NXV * 8;

    __shared__ ushort sB[NYR * NXV * LVS];

    const int rg = (blockIdx.x & 7) * ((int)gridDim.x >> 3) + (blockIdx.x >> 3);
    const int y0 = (rg % YG) * RY;
    const int z = (rg / YG) % DO;
    const int b = rg / (YG * DO);
    const int wave = threadIdx.x >> 6;
    const int lane = threadIdx.x & 63;
    const int n_l = lane & 15;
    const int q = lane >> 4;
    const int mt0 = (blockIdx.y * 4 + wave) * NCT;

    f32x4 acc[NCT][RY][NX];
    #pragma unroll
    for (int a = 0; a < NCT; ++a)
        #pragma unroll
        for (int r = 0; r < RY; ++r)
            #pragma unroll
            for (int c = 0; c < NX; ++c)
                acc[a][r][c] = (f32x4){0.f, 0.f, 0.f, 0.f};

    #pragma unroll 1
    for (int ct = 0; ct < NCI; ++ct) {
        #pragma unroll 1
        for (int dz = 0; dz < 3; ++dz) {
            int zp = z + dz - 1;
            bool vz = (unsigned)zp < (unsigned)DI;
            int zpc = vz ? zp : 0;
            __syncthreads();
            for (int g = threadIdx.x; g < NGRP; g += 256) {
                int r = g / (NXV * 8);
                int rem = g - r * (NXV * 8);
                int xv = rem >> 3;
                int gg = rem & 7;
                int yp = y0 + r - 1;
                bool v = vz & ((unsigned)yp < (unsigned)DI);
                long src = v ? ((((((long)b * DI + zpc) * DI + yp) * (DI + 1)) * CV + CV)
                                + (long)(xv - 1) * CV + ct * 64 + gg * 8)
                             : (long)(ct * 64 + gg * 8);   // zeroed lead pad
                *(bf16x8*)(sB + (r * NXV + xv) * LVS + gg * 8) = *(const bf16x8*)(inp + src);
            }
            __syncthreads();
            #pragma unroll 1
            for (int dy = 0; dy < 3; ++dy) {
                #pragma unroll
                for (int dx = 0; dx < 3; ++dx) {
                    const int tap = dz * 9 + dy * 3 + dx;
                    bf16x8 bh[RY][NX], bl[RY][NX];
                    #pragma unroll
                    for (int ry = 0; ry < RY; ++ry)
                        #pragma unroll
                        for (int nx = 0; nx < NX; ++nx) {
                            int xv = nx * 16 + n_l + dx;
                            const ushort* p = sB + ((ry + dy) * NXV + xv) * LVS + q * 16;
                            bh[ry][nx] = *(const bf16x8*)p;
                            bl[ry][nx] = *(const bf16x8*)(p + 8);
                        }
                    bf16x8 ahf[NCT], alf[NCT];
                    #pragma unroll
                    for (int mt = 0; mt < NCT; ++mt) {
                        size_t aa = ((size_t)(tap * NCI + ct) * NMT + (mt0 + mt)) * 1024 + lane * 16;
                        ahf[mt] = *(const bf16x8*)(A + aa);
                        alf[mt] = *(const bf16x8*)(A + aa + 8);
                    }
                    #pragma unroll
                    for (int mt = 0; mt < NCT; ++mt)
                        #pragma unroll
                        for (int ry = 0; ry < RY; ++ry)
                            #pragma unroll
                            for (int nx = 0; nx < NX; ++nx)
                                acc[mt][ry][nx] = __builtin_amdgcn_mfma_f32_16x16x32_bf16(ahf[mt], bh[ry][nx], acc[mt][ry][nx], 0, 0, 0);
                    #pragma unroll
                    for (int mt = 0; mt < NCT; ++mt)
                        #pragma unroll
                        for (int ry = 0; ry < RY; ++ry)
                            #pragma unroll
                            for (int nx = 0; nx < NX; ++nx)
                                acc[mt][ry][nx] = __builtin_amdgcn_mfma_f32_16x16x32_bf16(ahf[mt], bl[ry][nx], acc[mt][ry][nx], 0, 0, 0);
                    #pragma unroll
                    for (int mt = 0; mt < NCT; ++mt)
                        #pragma unroll
                        for (int ry = 0; ry < RY; ++ry)
                            #pragma unroll
                            for (int nx = 0; nx < NX; ++nx)
                                acc[mt][ry][nx] = __builtin_amdgcn_mfma_f32_16x16x32_bf16(alf[mt], bh[ry][nx], acc[mt][ry][nx], 0, 0, 0);
                }
            }
        }
    }

    #pragma unroll
    for (int ry = 0; ry < RY; ++ry) {
        int yo = y0 + ry;
        #pragma unroll
        for (int nx = 0; nx < NX; ++nx) {
            int xo = nx * 16 + n_l;
            size_t vb = ((((size_t)b * DO + z) * DO + yo) * (DO + 1)) * CVO + CVO + (size_t)xo * CVO;
            float mval = 1.f;
            if (EPI & EPI_MASK) mval = mask[(((size_t)b * DO + z) * DO + yo) * DO + xo];
            #pragma unroll
            for (int mt = 0; mt < NCT; ++mt) {
                int c0 = (mt0 + mt) * 16 + q * 4;
                size_t oa = vb + choff(c0);
                float rs[4] = {0.f, 0.f, 0.f, 0.f};
                if (EPI & EPI_RESID) {
                    us4 rh4 = *(const us4*)(resid + oa);
                    us4 rl4 = *(const us4*)(resid + oa + 8);
                    #pragma unroll
                    for (int r = 0; r < 4; ++r) rs[r] = bf2f(rh4[r]) + bf2f(rl4[r]);
                }
                us4 oh, ol;
                #pragma unroll
                for (int r = 0; r < 4; ++r) {
                    float v = acc[mt][ry][nx][r];
                    if (EPI & EPI_MASK) v *= mval;
                    if (EPI & EPI_RESID) v += rs[r];
                    if (EPI & EPI_LEAKY) v = leaky(v);
                    ushort hb = f2bf(v);
                    oh[r] = hb;
                    ol[r] = f2bf(v - bf2f(hb));
                }
                *(us4*)(outp + oa) = oh;
                *(us4*)(outp + oa + 8) = ol;
            }
        }
    }
}

// ---------------- MFMA conv v7: stage-3 convs (S=1, DO=16), K-split ----------
template<int CI, int CO, int DI, int RY, int NCT, int KS, int WPEU>
__global__ __launch_bounds__(256, WPEU) void mfma_conv7_kernel(
    const ushort* __restrict__ inp, const ushort* __restrict__ A,
    float* __restrict__ part)
{
    constexpr int DO = DI;
    constexpr int NCI = CI / 32;
    constexpr int KCI = NCI / KS;
    constexpr int NMT = CO / 16;
    constexpr int CV = CI * 2;
    constexpr int YG = DO / RY;
    constexpr int NYR = RY + 2;
    constexpr int NXV = DO + 2;
    constexpr int LVS = 72;
    constexpr int NCOG = NMT / (4 * NCT);
    constexpr int D3 = DO * DO * DO;

    __shared__ ushort sB[3 * NYR * NXV * LVS];

    const int rg = (blockIdx.x & 7) * ((int)gridDim.x >> 3) + (blockIdx.x >> 3);
    const int y0 = (rg % YG) * RY;
    const int z = (rg / YG) % DO;
    const int b = rg / (YG * DO);
    const int wave = threadIdx.x >> 6;
    const int lane = threadIdx.x & 63;
    const int n_l = lane & 15;
    const int q = lane >> 4;
    const int cog = blockIdx.y % NCOG;
    const int kc = blockIdx.y / NCOG;
    const int mt0 = (cog * 4 + wave) * NCT;

    f32x4 acc[NCT][RY];
    #pragma unroll
    for (int a = 0; a < NCT; ++a)
        #pragma unroll
        for (int r = 0; r < RY; ++r)
            acc[a][r] = (f32x4){0.f, 0.f, 0.f, 0.f};

    #pragma unroll 1
    for (int ctl = 0; ctl < KCI; ++ctl) {
        const int ct = kc * KCI + ctl;
        __syncthreads();
        for (int g = threadIdx.x; g < 3 * NYR * NXV * 8; g += 256) {
            int row = g / (NXV * 8);
            int rem = g - row * (NXV * 8);
            int xv = rem >> 3;
            int gg = rem & 7;
            int zi = row / NYR, yr = row - zi * NYR;
            int zp = z + zi - 1;
            int yp = y0 + yr - 1;
            bool v = ((unsigned)zp < (unsigned)DI) & ((unsigned)yp < (unsigned)DI);
            long src = v ? ((((((long)b * DI + zp) * DI + yp) * (DI + 1)) * CV + CV)
                            + (long)(xv - 1) * CV + ct * 64 + gg * 8)
                         : (long)(ct * 64 + gg * 8);
            *(bf16x8*)(sB + (row * NXV + xv) * LVS + gg * 8) = *(const bf16x8*)(inp + src);
        }
        __syncthreads();
        #pragma unroll 1
        for (int dz = 0; dz < 3; ++dz) {
            #pragma unroll 1
            for (int dy = 0; dy < 3; ++dy) {
                #pragma unroll
                for (int dx = 0; dx < 3; ++dx) {
                    const int tap = dz * 9 + dy * 3 + dx;
                    bf16x8 bh[RY], bl[RY];
                    #pragma unroll
                    for (int ry = 0; ry < RY; ++ry) {
                        const ushort* p = sB + ((dz * NYR + ry + dy) * NXV + n_l + dx) * LVS + q * 16;
                        bh[ry] = *(const bf16x8*)p;
                        bl[ry] = *(const bf16x8*)(p + 8);
                    }
                    bf16x8 ahf[NCT], alf[NCT];
                    #pragma unroll
                    for (int mt = 0; mt < NCT; ++mt) {
                        size_t aa = ((size_t)(tap * NCI + ct) * NMT + (mt0 + mt)) * 1024 + lane * 16;
                        ahf[mt] = *(const bf16x8*)(A + aa);
                        alf[mt] = *(const bf16x8*)(A + aa + 8);
                    }
                    #pragma unroll
                    for (int mt = 0; mt < NCT; ++mt)
                        #pragma unroll
                        for (int ry = 0; ry < RY; ++ry)
                            acc[mt][ry] = __builtin_amdgcn_mfma_f32_16x16x32_bf16(ahf[mt], bh[ry], acc[mt][ry], 0, 0, 0);
                    #pragma unroll
                    for (int mt = 0; mt < NCT; ++mt)
                        #pragma unroll
                        for (int ry = 0; ry < RY; ++ry)
                            acc[mt][ry] = __builtin_amdgcn_mfma_f32_16x16x32_bf16(ahf[mt], bl[ry], acc[mt][ry], 0, 0, 0);
                    #pragma unroll
                    for (int mt = 0; mt < NCT; ++mt)
                        #pragma unroll
                        for (int ry = 0; ry < RY; ++ry)
                            acc[mt][ry] = __builtin_amdgcn_mfma_f32_16x16x32_bf16(alf[mt], bh[ry], acc[mt][ry], 0, 0, 0);
                }
            }
        }
    }

    #pragma unroll
    for (int ry = 0; ry < RY; ++ry) {
        int yo = y0 + ry;
        int v = (z * DO + yo) * DO + n_l;
        #pragma unroll
        for (int mt = 0; mt < NCT; ++mt) {
            int c0 = (mt0 + mt) * 16 + q * 4;
            size_t off = (((size_t)kc * 2 + b) * D3 + v) * CO + c0;
            *(f32x4*)(part + off) = acc[mt][ry];
        }
    }
}

// ---------------- combine3: sum K-split halves + epilogue -> interleaved CL ---
__global__ __launch_bounds__(256) void combine3_kernel(
    const float* __restrict__ part, const float* __restrict__ mask,
    const ushort* __restrict__ resid, ushort* __restrict__ outp)
{
    int i = blockIdx.x * 256 + threadIdx.x;      // over 2*4096*64
    if (i >= 2 * 4096 * 64) return;
    int g = i & 63, v = (i >> 6) & 4095, b = i >> 18;
    int c0 = g * 4;
    size_t p0 = (((size_t)b) * 4096 + v) * 256 + c0;
    float4 s0 = *(const float4*)(part + p0);
    float4 s1 = *(const float4*)(part + p0 + (size_t)2 * 4096 * 256);
    float m = mask[b * 4096 + v];
    int z = v >> 8, y = (v >> 4) & 15, x = v & 15;
    size_t vb = ((((size_t)b * 16 + z) * 16 + y) * 17) * 512 + 512 + (size_t)x * 512;
    size_t oa = vb + choff(c0);
    float rs[4] = {0.f, 0.f, 0.f, 0.f};
    if (resid) {
        us4 rh = *(const us4*)(resid + oa);
        us4 rl = *(const us4*)(resid + oa + 8);
        #pragma unroll
        for (int r = 0; r < 4; ++r) rs[r] = bf2f(rh[r]) + bf2f(rl[r]);
    }
    float sv[4] = {s0.x + s1.x, s0.y + s1.y, s0.z + s1.z, s0.w + s1.w};
    us4 oh, ol;
    #pragma unroll
    for (int r = 0; r < 4; ++r) {
        float val = sv[r] * m + rs[r];
        val = leaky(val);
        ushort hb = f2bf(val);
        oh[r] = hb;
        ol[r] = f2bf(val - bf2f(hb));
    }
    *(us4*)(outp + oa) = oh;
    *(us4*)(outp + oa + 8) = ol;
}

// ---------------- wd3 via MFMA (product-major) -> x4 fp32 ---------------------
__global__ __launch_bounds__(256) void wd3_mfma_kernel(
    const ushort* __restrict__ x3, const ushort* __restrict__ A,
    float* __restrict__ x4)
{
    constexpr int NCI = 8;   // 256/32
    constexpr int NMT = 8;   // 128/16
    const int blk = blockIdx.x;
    const int yg = blk & 3;
    const int z = (blk >> 2) & 7;
    const int b = blk >> 5;
    const int wave = threadIdx.x >> 6;
    const int lane = threadIdx.x & 63;
    const int n_l = lane & 15;
    const int q = lane >> 4;
    const int y = yg * 2 + (n_l >> 3);
    const int x = n_l & 7;
    const int mt0 = wave * 2;

    f32x4 acc[2];
    acc[0] = (f32x4){0.f, 0.f, 0.f, 0.f};
    acc[1] = (f32x4){0.f, 0.f, 0.f, 0.f};
    const bf16x8 zero8 = {0, 0, 0, 0, 0, 0, 0, 0};

    for (int ct = 0; ct < NCI; ++ct) {
        #pragma unroll
        for (int dz = 0; dz < 3; ++dz) {
            int zp = 2 * z + dz - 1;
            if ((unsigned)zp >= 16u) continue;
            #pragma unroll
            for (int dy = 0; dy < 3; ++dy) {
                int yp = 2 * y + dy - 1;
                bool vy = (unsigned)yp < 16u;
                int ypc = vy ? yp : 0;
                #pragma unroll
                for (int dx = 0; dx < 3; ++dx) {
                    int xp = 2 * x + dx - 1;
                    int tap = dz * 9 + dy * 3 + dx;
                    size_t ba = ((((size_t)b * 16 + zp) * 16 + ypc) * 17 + 1 + xp) * 512
                              + ct * 64 + q * 16;
                    bf16x8 bh = vy ? *(const bf16x8*)(x3 + ba) : zero8;
                    bf16x8 bl = vy ? *(const bf16x8*)(x3 + ba + 8) : zero8;
                    bf16x8 ahf[2], alf[2];
                    #pragma unroll
                    for (int mt = 0; mt < 2; ++mt) {
                        size_t aa = ((size_t)(tap * NCI + ct) * NMT + (mt0 + mt)) * 1024 + lane * 16;
                        ahf[mt] = *(const bf16x8*)(A + aa);
                        alf[mt] = *(const bf16x8*)(A + aa + 8);
                    }
                    #pragma unroll
                    for (int mt = 0; mt < 2; ++mt)
                        acc[mt] = __builtin_amdgcn_mfma_f32_16x16x32_bf16(ahf[mt], bh, acc[mt], 0, 0, 0);
                    #pragma unroll
                    for (int mt = 0; mt < 2; ++mt)
                        acc[mt] = __builtin_amdgcn_mfma_f32_16x16x32_bf16(ahf[mt], bl, acc[mt], 0, 0, 0);
                    #pragma unroll
                    for (int mt = 0; mt < 2; ++mt)
                        acc[mt] = __builtin_amdgcn_mfma_f32_16x16x32_bf16(alf[mt], bh, acc[mt], 0, 0, 0);
                }
            }
        }
    }
    #pragma unroll
    for (int mt = 0; mt < 2; ++mt)
        #pragma unroll
        for (int r = 0; r < 4; ++r) {
            int co = (mt0 + mt) * 16 + q * 4 + r;
            x4[((size_t)(b * 128 + co)) * 512 + z * 64 + y * 8 + x] = leaky(acc[mt][r]);
        }
}

// ---------------- final: mean/max pool over 8^3 -------------------------------
__global__ __launch_bounds__(64) void reduce_kernel(
    const float* __restrict__ x4, float* __restrict__ out)
{
    int bc = blockIdx.x;
    int b = bc >> 7, c = bc & 127;
    const float* p = x4 + (size_t)(b * 128 + c) * 512;
    float s = 0.f, mx = -3.4e38f;
    for (int i = threadIdx.x; i < 512; i += 64) {
        float v = p[i];
        s += v;
        mx = fmaxf(mx, v);
    }
    #pragma unroll
    for (int o = 32; o > 0; o >>= 1) {
        s += __shfl_down(s, o);
        mx = fmaxf(mx, __shfl_down(mx, o));
    }
    if (threadIdx.x == 0) {
        out[b * 256 + c] = s * (1.f / 512.f);
        out[b * 256 + 128 + c] = mx;
    }
}

__global__ __launch_bounds__(256) void zero_out_kernel(float* __restrict__ out, int n)
{
    int i = blockIdx.x * 256 + threadIdx.x;
    if (i < n) out[i] = 0.f;
}

// ---------------------------------------------------------------------------
extern "C" void kernel_launch(void* const* d_in, const int* in_sizes, int n_in,
                              void* d_out, int out_size, void* d_ws, size_t ws_size,
                              hipStream_t stream)
{
    (void)in_sizes; (void)n_in;
    const float* x    = (const float*)d_in[0];
    const float* mask = (const float*)d_in[1];
    const float* w1a  = (const float*)d_in[2];
    const float* w1b  = (const float*)d_in[3];
    const float* w1d  = (const float*)d_in[4];
    const float* wd1  = (const float*)d_in[5];
    const float* w2a  = (const float*)d_in[6];
    const float* w2b  = (const float*)d_in[7];
    const float* wd2  = (const float*)d_in[8];
    const float* w3a  = (const float*)d_in[9];
    const float* w3b  = (const float*)d_in[10];
    const float* wd3  = (const float*)d_in[11];
    float* out = (float*)d_out;
    char* ws = (char*)d_ws;

    const size_t RSZ = 34603520;      // stage-2 tensor region (interleaved)
    const size_t SZ3 = 8913920;       // stage-3 tensor bytes
    const size_t POFF = 9437184;      // partial-buffer offset within R2/R3
    char* R1 = ws;
    char* R2 = ws + RSZ;
    char* R3 = ws + 2 * RSZ;
    size_t off = 3 * RSZ;
    auto alloc = [&](size_t bytes) { char* p = ws + off; off = (off + bytes + 255) & ~255ull; return p; };
    ushort* pk2a = (ushort*)alloc(1769472);
    ushort* pk2b = (ushort*)alloc(1769472);
    ushort* pkd2 = (ushort*)alloc(3538944);
    ushort* pk3a = (ushort*)alloc(7077888);
    ushort* pk3b = (ushort*)alloc(7077888);
    float*  wd1P = (float*)alloc(884736);
    float*  waT  = (float*)alloc(20736);
    float*  w1bT = (float*)alloc(442368);
    float*  wdTt = (float*)alloc(768);
    float*  m2   = (float*)alloc(262144);
    float*  m3   = (float*)alloc(32768);
    int*    cnt  = (int*)alloc(256);
    const size_t NEED = off;

    if (ws_size < NEED) {
        zero_out_kernel<<<dim3((out_size + 255) / 256), 256, 0, stream>>>(out, out_size);
        return;
    }

    // stage-1 scratch aliased into R2 (dead before t2 is written)
    float* t1c  = (float*)R2;
    float* x1c  = (float*)(R2 + 8388608);
    int*   idx  = (int*)(R2 + 16777216);
    int*   list = (int*)(R2 + 18874368);
    // late-phase aliases
    ushort* pkd3 = (ushort*)R1;       // xin3 dead after conv3b combine
    float*  x4   = (float*)R2;        // t3 dead after conv3b conv
    float*  part3a = (float*)(R2 + POFF);
    float*  part3b = (float*)(R3 + POFF);

    ushort* xin2 = (ushort*)R1;
    ushort* t2   = (ushort*)R2;
    ushort* x2   = (ushort*)R3;
    ushort* xin3 = (ushort*)R1;
    ushort* t3   = (ushort*)R2;
    ushort* x3   = (ushort*)R3;

    // stage-2 layout pads: 2048 rows, slotstride 33*256, slotsize 256 ushorts
    // stage-3 layout pads: 512 rows, slotstride 17*512, slotsize 512 ushorts
    auto pad2 = [&](void* base) {
        pad_zero_kernel<<<dim3((2049 * 32 + 255) / 256), 256, 0, stream>>>(
            (ushort*)base, 2048, 33 * 256, 256);
    };
    auto pad3 = [&](void* base) {
        pad_zero_kernel<<<dim3((513 * 64 + 255) / 256), 256, 0, stream>>>(
            (ushort*)base, 512, 17 * 512, 512);
    };

    hipMemsetAsync(cnt, 0, 4, stream);
    hipMemsetAsync(idx, 0xFF, 2097152, stream);
    pad2(R1);                                     // xin2 pads only

    auto tg = [](int n) { return dim3((n + 255) / 256); };
    pack_w_kernel<<<tg(27 * 128 * 128 * 2), 256, 0, stream>>>(w2a, pk2a, 128, 128);
    pack_w_kernel<<<tg(27 * 128 * 128 * 2), 256, 0, stream>>>(w2b, pk2b, 128, 128);
    pack_w_kernel<<<tg(27 * 128 * 256 * 2), 256, 0, stream>>>(wd2, pkd2, 128, 256);
    pack_w_kernel<<<tg(27 * 256 * 256 * 2), 256, 0, stream>>>(w3a, pk3a, 256, 256);
    pack_w_kernel<<<tg(27 * 256 * 256 * 2), 256, 0, stream>>>(w3b, pk3b, 256, 256);
    pack_wd1_kernel    <<<tg(27 * 64 * 128), 256, 0, stream>>>(wd1, wd1P);
    transpose_w_kernel <<<tg(64 * 81),    256, 0, stream>>>(w1a, waT,  64, 81);
    pack_w1b_kernel    <<<tg(27 * 64 * 64), 256, 0, stream>>>(w1b, w1bT);
    transpose_w_kernel <<<tg(64 * 3),     256, 0, stream>>>(w1d, wdTt, 64, 3);

    maxpool_kernel<64, 32><<<dim3(2 * 32768 / 256), 256, 0, stream>>>(mask, m2);
    maxpool_kernel<32, 16><<<dim3(2 * 4096 / 256),  256, 0, stream>>>(m2, m3);
    build_list_kernel<<<dim3(2 * 262144 / 256), 256, 0, stream>>>(mask, list, idx, cnt);

    // stage 1 (sparse, fp32)
    stage1a_kernel<<<dim3(2048), 64, 0, stream>>>(x, waT, list, cnt, t1c);
    stage1b_kernel<<<dim3(ROWCAP), 64, 0, stream>>>(t1c, x, w1bT, wdTt, list, idx, cnt, x1c);
    wd1_kernel<<<dim3(32768, 2), 128, 0, stream>>>(x1c, idx, wd1P, xin2);

    // stage-1 scratch dead; zero t2/x2 pads only
    pad2(R2);
    pad2(R3);

    // stage2 res block: conv8 slab staging (RY=2/NX=2/NCT=2, 1024 blocks)
    mfma_conv8_kernel<128, 128, 32, 2, 2, 2, 4, EPI_MASK | EPI_LEAKY>
        <<<dim3(1024, 1), 256, 0, stream>>>(xin2, pk2a, m2, nullptr, t2);
    mfma_conv8_kernel<128, 128, 32, 2, 2, 2, 4, EPI_MASK | EPI_RESID | EPI_LEAKY>
        <<<dim3(1024, 1), 256, 0, stream>>>(t2, pk2b, m2, xin2, x2);

    // xin2 dead -> zero xin3 pads; wd2 (conv6)
    pad3(R1);
    mfma_conv6_kernel<128, 256, 32, 16, 2, 2, 1, 2, 4, EPI_LEAKY>
        <<<dim3(256, 2), 256, 0, stream>>>(x2, pkd2, nullptr, nullptr, xin3);

    // conv3a: conv7 (K-split) -> partials; combine -> t3
    pad3(R2);
    mfma_conv7_kernel<256, 256, 16, 2, 2, 2, 4>
        <<<dim3(256, 4), 256, 0, stream>>>(xin3, pk3a, part3a);
    combine3_kernel<<<dim3(2048), 256, 0, stream>>>(part3a, m3, nullptr, t3);

    // conv3b: conv7 -> partials; combine (resid=xin3) -> x3
    pad3(R3);
    mfma_conv7_kernel<256, 256, 16, 2, 2, 2, 4>
        <<<dim3(256, 4), 256, 0, stream>>>(t3, pk3b, part3b);
    combine3_kernel<<<dim3(2048), 256, 0, stream>>>(part3b, m3, xin3, x3);

    // xin3 (R1) and t3 (R2) dead: pack wd3 -> R1, MFMA wd3 -> x4 (R2)
    pack_w_kernel<<<tg(27 * 256 * 128 * 2), 256, 0, stream>>>(wd3, pkd3, 256, 128);
    wd3_mfma_kernel<<<dim3(64), 256, 0, stream>>>(x3, pkd3, x4);

    reduce_kernel<<<dim3(256), 64, 0, stream>>>(x4, out);
}

// Round 22
// 1041.398 us; speedup vs baseline: 1.1253x; 1.0243x over previous
//
#include <hip/hip_runtime.h>

// ---------------------------------------------------------------------------
// SparseEncoderResUNet on MI355X — round 22: launch fusion.
// r21: 1067us, flat profile; top kernel conv8 at MfmaUtil 59 + VALU 25 = 84%
// combined (structural ceiling for this K-loop shape per r11-r14). Remaining
// waste: ~25 dispatches with ~2-4us gaps. Fusions (all bit-identical):
//   - 5 MFMA weight packs -> pack5_kernel (wd3 pack stays late: aliases xin3)
//   - 4 stage-1 weight preps -> pack_s1_kernel
//   - build_list + maxpool64->32 -> mask_front_kernel
//   - pad2(R2)+pad2(R3) -> pad_zero2; pad3(R1)+pad3(R2) -> pad_zero2 (hoisted
//     after conv8-b where xin2/t2 die)
// ---------------------------------------------------------------------------

enum { EPI_MASK = 1, EPI_LEAKY = 2, EPI_RESID = 4 };
#define ROWCAP 32768

typedef short  bf16x8 __attribute__((ext_vector_type(8)));
typedef float  f32x4  __attribute__((ext_vector_type(4)));
typedef ushort us4    __attribute__((ext_vector_type(4)));

__device__ __forceinline__ float leaky(float v) { return v >= 0.f ? v : 0.2f * v; }
__device__ __forceinline__ ushort f2bf(float f) {
    unsigned u = __float_as_uint(f);
    return (ushort)((u + 0x7FFFu + ((u >> 16) & 1u)) >> 16);
}
__device__ __forceinline__ float bf2f(ushort h) {
    return __uint_as_float((unsigned)h << 16);
}
// channel c -> offset within a voxel's CI*2 block (interleaved hi/lo by 8)
__device__ __forceinline__ int choff(int c) {
    return (c >> 5) * 64 + ((c >> 3) & 3) * 16 + (c & 7);
}

// ---------------- pad-slot zeroing (1 or 2 bases) ----------------------------
__global__ __launch_bounds__(256) void pad_zero_kernel(
    ushort* __restrict__ base, int nrows, int slotstride, int slotsize)
{
    int i = blockIdx.x * 256 + threadIdx.x;
    int per = slotsize >> 3;
    int total = (nrows + 1) * per;
    if (i >= total) return;
    int slot = i / per, w = i - slot * per;
    *(uint4*)(base + (size_t)slot * slotstride + w * 8) = make_uint4(0, 0, 0, 0);
}

__global__ __launch_bounds__(256) void pad_zero2_kernel(
    ushort* __restrict__ base1, ushort* __restrict__ base2,
    int nrows, int slotstride, int slotsize)
{
    int i = blockIdx.x * 256 + threadIdx.x;
    int per = slotsize >> 3;
    int total = (nrows + 1) * per;
    ushort* base = base1;
    if (i >= total) {
        i -= total;
        base = base2;
        if (i >= total) return;
    }
    int slot = i / per, w = i - slot * per;
    *(uint4*)(base + (size_t)slot * slotstride + w * 8) = make_uint4(0, 0, 0, 0);
}

// ---------------- batched MFMA weight packs ----------------------------------
__device__ __forceinline__ void pack_one(const float* __restrict__ w,
                                         ushort* __restrict__ A,
                                         int CI, int CO, int i)
{
    int j = i & 7, hilo = (i >> 3) & 1, L = (i >> 4) & 63, rest = i >> 10;
    int NMT = CO >> 4, NCI = CI >> 5;
    int mt = rest % NMT; rest /= NMT;
    int ct = rest % NCI;
    int tap = rest / NCI;
    int co = mt * 16 + (L & 15);
    int ci = ct * 32 + (L >> 4) * 8 + j;
    float v = w[((size_t)co * CI + ci) * 27 + tap];
    ushort h = f2bf(v);
    A[i] = hilo ? f2bf(v - bf2f(h)) : h;
}

// 5 packs in one grid (w2a, w2b, wd2, w3a, w3b)
__global__ __launch_bounds__(256) void pack5_kernel(
    const float* __restrict__ w2a, ushort* __restrict__ A2a,
    const float* __restrict__ w2b, ushort* __restrict__ A2b,
    const float* __restrict__ wd2, ushort* __restrict__ Ad2,
    const float* __restrict__ w3a, ushort* __restrict__ A3a,
    const float* __restrict__ w3b, ushort* __restrict__ A3b)
{
    const int N128  = 27 * 128 * 128 * 2;   // 884736
    const int N128B = 27 * 128 * 256 * 2;   // 1769472
    const int N256  = 27 * 256 * 256 * 2;   // 3538944
    int i = blockIdx.x * 256 + threadIdx.x;
    if (i < N128)            { pack_one(w2a, A2a, 128, 128, i); return; }
    i -= N128;
    if (i < N128)            { pack_one(w2b, A2b, 128, 128, i); return; }
    i -= N128;
    if (i < N128B)           { pack_one(wd2, Ad2, 128, 256, i); return; }
    i -= N128B;
    if (i < N256)            { pack_one(w3a, A3a, 256, 256, i); return; }
    i -= N256;
    if (i < N256)            { pack_one(w3b, A3b, 256, 256, i); }
}

// wd3 pack (single, must run late: destination aliases xin3)
__global__ __launch_bounds__(256) void pack_w_kernel(
    const float* __restrict__ w, ushort* __restrict__ A, int CI, int CO)
{
    int i = blockIdx.x * 256 + threadIdx.x;
    if (i >= 27 * CI * CO * 2) return;
    pack_one(w, A, CI, CO, i);
}

// ---------------- stage-1 weight preps, batched ------------------------------
__global__ __launch_bounds__(256) void pack_s1_kernel(
    const float* __restrict__ wd1, float* __restrict__ wd1P,
    const float* __restrict__ w1a, float* __restrict__ waT,
    const float* __restrict__ w1b, float* __restrict__ w1bT,
    const float* __restrict__ w1d, float* __restrict__ wdTt)
{
    int i = blockIdx.x * 256 + threadIdx.x;
    if (i < 221184) {                       // wd1P[t][ci][co], co=128
        int co = i & 127, ci = (i >> 7) & 63, t = i >> 13;
        wd1P[i] = wd1[(co * 64 + ci) * 27 + t];
        return;
    }
    i -= 221184;
    if (i < 5184) {                          // waT[r][co], CO=64, CIK=81
        int co = i / 81, r = i - co * 81;
        waT[r * 64 + co] = w1a[i];
        return;
    }
    i -= 5184;
    if (i < 110592) {                        // w1bT[t][ci][co], co=64
        int co = i & 63, ci = (i >> 6) & 63, t = i >> 12;
        w1bT[i] = w1b[(co * 64 + ci) * 27 + t];
        return;
    }
    i -= 110592;
    if (i < 192) {                           // wdTt[r][co], CO=64, CIK=3
        int co = i / 3, r = i - co * 3;
        wdTt[r * 64 + co] = w1d[i];
    }
}

// ---------------- fused build_list + maxpool 64->32 --------------------------
__global__ __launch_bounds__(256) void mask_front_kernel(
    const float* __restrict__ m, int* __restrict__ list, int* __restrict__ idxmap,
    int* __restrict__ count, float* __restrict__ m2)
{
    int i = blockIdx.x * 256 + threadIdx.x;
    if (i < 2 * 262144) {
        if (m[i] > 0.5f) {
            int k = atomicAdd(count, 1);
            if (k < ROWCAP) {
                list[k] = i;
                idxmap[i] = k;
            }
        }
        return;
    }
    i -= 2 * 262144;
    if (i >= 2 * 32768) return;
    int b = i >> 15;
    int v = i & 32767;
    int z = v >> 10, y = (v >> 5) & 31, x = v & 31;
    float mx = 0.f;
    #pragma unroll
    for (int dz = 0; dz < 3; ++dz)
        #pragma unroll
        for (int dy = 0; dy < 3; ++dy)
            #pragma unroll
            for (int dx = 0; dx < 3; ++dx) {
                int zi = 2 * z - 1 + dz, yi = 2 * y - 1 + dy, xi = 2 * x - 1 + dx;
                if ((unsigned)zi < 64u && (unsigned)yi < 64u && (unsigned)xi < 64u)
                    mx = fmaxf(mx, m[(size_t)b * 262144 + (zi << 12) + (yi << 6) + xi]);
            }
    m2[i] = mx;
}

// ---------------- maxpool k3 s2 p1 (m2 -> m3) --------------------------------
template<int DIN, int DOUT>
__global__ __launch_bounds__(256) void maxpool_kernel(
    const float* __restrict__ in, float* __restrict__ out)
{
    int i = blockIdx.x * 256 + threadIdx.x;
    constexpr int D3O = DOUT * DOUT * DOUT;
    if (i >= 2 * D3O) return;
    int b = i / D3O;
    int v = i - b * D3O;
    int z = v / (DOUT * DOUT), y = (v / DOUT) % DOUT, x = v % DOUT;
    float mx = 0.f;
    #pragma unroll
    for (int dz = 0; dz < 3; ++dz)
        #pragma unroll
        for (int dy = 0; dy < 3; ++dy)
            #pragma unroll
            for (int dx = 0; dx < 3; ++dx) {
                int zi = 2 * z - 1 + dz, yi = 2 * y - 1 + dy, xi = 2 * x - 1 + dx;
                if ((unsigned)zi < (unsigned)DIN && (unsigned)yi < (unsigned)DIN &&
                    (unsigned)xi < (unsigned)DIN)
                    mx = fmaxf(mx, in[(size_t)b * DIN * DIN * DIN + (zi * DIN + yi) * DIN + xi]);
            }
    out[i] = mx;
}

// ---------------- stage1 conv-a (3->64, gathered) -> t1c[row][64] -------------
__global__ __launch_bounds__(64) void stage1a_kernel(
    const float* __restrict__ x, const float* __restrict__ waT,
    const int* __restrict__ list, const int* __restrict__ count,
    float* __restrict__ t1c)
{
    __shared__ float smem[81];
    int n = min(*count, ROWCAP);
    for (int i = blockIdx.x; i < n; i += gridDim.x) {
        int lin = list[i];
        int b = lin >> 18;
        int v = lin & 262143;
        int z = v >> 12, y = (v >> 6) & 63, xx = v & 63;
        for (int j = threadIdx.x; j < 81; j += 64) {
            int ci = j / 27, t = j - ci * 27;
            int zz = z + t / 9 - 1, yy = y + (t / 3) % 3 - 1, xc = xx + t % 3 - 1;
            float val = 0.f;
            if ((unsigned)zz < 64u && (unsigned)yy < 64u && (unsigned)xc < 64u)
                val = x[(size_t)(b * 3 + ci) * 262144 + (zz << 12) + (yy << 6) + xc];
            smem[j] = val;
        }
        __syncthreads();
        float acc = 0.f;
        #pragma unroll 9
        for (int j = 0; j < 81; ++j)
            acc = fmaf(smem[j], waT[j * 64 + threadIdx.x], acc);
        t1c[(size_t)i * 64 + threadIdx.x] = leaky(acc);
        __syncthreads();
    }
}

// ---------------- stage1 conv-b v3: ballot-compacted sparse taps --------------
__global__ __launch_bounds__(64) void stage1b_kernel(
    const float* __restrict__ t1c, const float* __restrict__ x,
    const float* __restrict__ w1bT,  // [27][64][64] (tap, ci, co)
    const float* __restrict__ wdT,   // [3][64]
    const int* __restrict__ list, const int* __restrict__ idxmap,
    const int* __restrict__ count,
    float* __restrict__ x1c)
{
    __shared__ int   srr[27];
    __shared__ float sx[27][64];
    int n = min(*count, ROWCAP);
    int i = blockIdx.x;
    if (i >= n) return;
    const int tid = threadIdx.x;
    int lin = list[i];
    int b = lin >> 18;
    int v = lin & 262143;
    int z = v >> 12, y = (v >> 6) & 63, xx = v & 63;
    const int* im = idxmap + b * 262144;

    int r = -1;
    if (tid < 27) {
        int kz = tid / 9, ky = (tid / 3) % 3, kx = tid % 3;
        int zz = z + kz - 1, yy = y + ky - 1, xc = xx + kx - 1;
        if ((unsigned)zz < 64u && (unsigned)yy < 64u && (unsigned)xc < 64u)
            r = im[(zz << 12) + (yy << 6) + xc];
        srr[tid] = r;
    }
    unsigned long long mask = __ballot(r >= 0);   // single wave
    __syncthreads();
    unsigned long long mm = mask;
    while (mm) {
        int t = __ffsll((unsigned long long)mm) - 1;
        mm &= mm - 1;
        sx[t][tid] = t1c[(size_t)srr[t] * 64 + tid];
    }
    __syncthreads();

    float acc = 0.f;
    mm = mask;
    while (mm) {
        int t = __ffsll((unsigned long long)mm) - 1;
        mm &= mm - 1;
        const float* wp = w1bT + (size_t)t * 4096 + tid;
        const float* xr = sx[t];
        #pragma unroll 8
        for (int ci = 0; ci < 64; ++ci)
            acc = fmaf(xr[ci], wp[ci * 64], acc);
    }
    float id = 0.f;
    #pragma unroll
    for (int ci = 0; ci < 3; ++ci)
        id = fmaf(x[(size_t)(b * 3 + ci) * 262144 + v], wdT[ci * 64 + tid], id);
    x1c[(size_t)i * 64 + tid] = leaky(acc + id);
}

// ---------------- wd1 v5: 128 threads, packed weights, ballot taps ------------
__global__ __launch_bounds__(128) void wd1_kernel(
    const float* __restrict__ x1c, const int* __restrict__ idxmap,
    const float* __restrict__ wP,   // [27][64][128] (tap, ci, co)
    ushort* __restrict__ outp)
{
    __shared__ int   srr[27];
    __shared__ unsigned long long smask;
    __shared__ float sx[27][64];
    const int tid = threadIdx.x;
    const int v = blockIdx.x;           // 0..32767
    const int b = blockIdx.y;
    const int zo = v >> 10, yo = (v >> 5) & 31, xo = v & 31;
    const int* im = idxmap + b * 262144;

    int r = -1;
    if (tid < 27) {
        int kz = tid / 9, ky = (tid / 3) % 3, kx = tid % 3;
        int zi = 2 * zo - 1 + kz, yi = 2 * yo - 1 + ky, xi = 2 * xo - 1 + kx;
        if ((unsigned)zi < 64u && (unsigned)yi < 64u && (unsigned)xi < 64u)
            r = im[(zi << 12) + (yi << 6) + xi];
        srr[tid] = r;
    }
    if (tid < 64) {
        unsigned long long m0 = __ballot(r >= 0);
        if (tid == 0) smask = m0;
    }
    __syncthreads();
    const unsigned long long mask = smask;

    unsigned long long mm = mask;
    while (mm) {
        int t = __ffsll((unsigned long long)mm) - 1;
        mm &= mm - 1;
        if (tid < 64)
            sx[t][tid] = x1c[(size_t)srr[t] * 64 + tid];
    }
    __syncthreads();

    float acc = 0.f;
    mm = mask;
    while (mm) {
        int t = __ffsll((unsigned long long)mm) - 1;
        mm &= mm - 1;
        const float* wp = wP + (size_t)t * 8192 + tid;
        const float* xr = sx[t];
        #pragma unroll 8
        for (int ci = 0; ci < 64; ++ci)
            acc = fmaf(xr[ci], wp[ci * 128], acc);
    }
    float val = leaky(acc);
    ushort hb = f2bf(val);
    ushort lb = f2bf(val - bf2f(hb));
    size_t vb = ((((size_t)b * 32 + zo) * 32 + yo) * 33 + xo) * 256 + 256;
    int off = choff(tid);
    outp[vb + off] = hb;
    outp[vb + off + 8] = lb;
}

// ---------------- MFMA conv v6: LDS-staged B (wd2) ----------------------------
template<int CI, int CO, int DI, int DO, int STRIDE, int RY, int NX, int NCT, int WPEU, int EPI>
__global__ __launch_bounds__(256, WPEU) void mfma_conv6_kernel(
    const ushort* __restrict__ inp, const ushort* __restrict__ A,
    const float* __restrict__ mask, const ushort* __restrict__ resid,
    ushort* __restrict__ outp)
{
    constexpr int NCI = CI / 32;
    constexpr int NMT = CO / 16;
    constexpr int CV = CI * 2;
    constexpr int CVO = CO * 2;
    constexpr int YG = DO / RY;
    constexpr int NXV = (DO - 1) * STRIDE + 3;
    constexpr int LVS = (STRIDE == 2) ? 68 : 72;
    constexpr int NGRP = RY * NXV * 8;

    __shared__ ushort sB[RY * NXV * LVS];

    const int rg = (blockIdx.x & 7) * ((int)gridDim.x >> 3) + (blockIdx.x >> 3);
    const int y0 = (rg % YG) * RY;
    const int z = (rg / YG) % DO;
    const int b = rg / (YG * DO);
    const int wave = threadIdx.x >> 6;
    const int lane = threadIdx.x & 63;
    const int n_l = lane & 15;
    const int q = lane >> 4;
    const int mt0 = (blockIdx.y * 4 + wave) * NCT;

    f32x4 acc[NCT][RY][NX];
    #pragma unroll
    for (int a = 0; a < NCT; ++a)
        #pragma unroll
        for (int r = 0; r < RY; ++r)
            #pragma unroll
            for (int c = 0; c < NX; ++c)
                acc[a][r][c] = (f32x4){0.f, 0.f, 0.f, 0.f};

    #pragma unroll 1
    for (int ct = 0; ct < NCI; ++ct) {
        #pragma unroll 1
        for (int dz = 0; dz < 3; ++dz) {
            int zp = z * STRIDE + dz - 1;
            bool vz = (unsigned)zp < (unsigned)DI;
            int zpc = vz ? zp : 0;
            #pragma unroll 1
            for (int dy = 0; dy < 3; ++dy) {
                long rowb[RY];
                #pragma unroll
                for (int ry = 0; ry < RY; ++ry) {
                    int yp = (y0 + ry) * STRIDE + dy - 1;
                    bool v = vz && ((unsigned)yp < (unsigned)DI);
                    rowb[ry] = v ? (((((long)b * DI + zpc) * DI + yp) * (DI + 1)) * CV + CV) : -1;
                }
                __syncthreads();
                for (int g = threadIdx.x; g < NGRP; g += 256) {
                    int r = g / (NXV * 8);
                    int rem = g - r * (NXV * 8);
                    int xv = rem >> 3;
                    int gg = rem & 7;
                    long src = (rowb[r] >= 0)
                             ? (rowb[r] + (long)(xv - 1) * CV + ct * 64 + gg * 8)
                             : (long)(ct * 64 + gg * 8);
                    *(bf16x8*)(sB + (r * NXV + xv) * LVS + gg * 8) = *(const bf16x8*)(inp + src);
                }
                __syncthreads();
                #pragma unroll
                for (int dx = 0; dx < 3; ++dx) {
                    const int tap = dz * 9 + dy * 3 + dx;
                    bf16x8 bh[RY][NX], bl[RY][NX];
                    #pragma unroll
                    for (int ry = 0; ry < RY; ++ry)
                        #pragma unroll
                        for (int nx = 0; nx < NX; ++nx) {
                            int xv = (nx * 16 + n_l) * STRIDE + dx;
                            const ushort* p = sB + (ry * NXV + xv) * LVS + q * 16;
                            bh[ry][nx] = *(const bf16x8*)p;
                            bl[ry][nx] = *(const bf16x8*)(p + 8);
                        }
                    bf16x8 ahf[NCT], alf[NCT];
                    #pragma unroll
                    for (int mt = 0; mt < NCT; ++mt) {
                        size_t aa = ((size_t)(tap * NCI + ct) * NMT + (mt0 + mt)) * 1024 + lane * 16;
                        ahf[mt] = *(const bf16x8*)(A + aa);
                        alf[mt] = *(const bf16x8*)(A + aa + 8);
                    }
                    #pragma unroll
                    for (int mt = 0; mt < NCT; ++mt)
                        #pragma unroll
                        for (int ry = 0; ry < RY; ++ry)
                            #pragma unroll
                            for (int nx = 0; nx < NX; ++nx)
                                acc[mt][ry][nx] = __builtin_amdgcn_mfma_f32_16x16x32_bf16(ahf[mt], bh[ry][nx], acc[mt][ry][nx], 0, 0, 0);
                    #pragma unroll
                    for (int mt = 0; mt < NCT; ++mt)
                        #pragma unroll
                        for (int ry = 0; ry < RY; ++ry)
                            #pragma unroll
                            for (int nx = 0; nx < NX; ++nx)
                                acc[mt][ry][nx] = __builtin_amdgcn_mfma_f32_16x16x32_bf16(ahf[mt], bl[ry][nx], acc[mt][ry][nx], 0, 0, 0);
                    #pragma unroll
                    for (int mt = 0; mt < NCT; ++mt)
                        #pragma unroll
                        for (int ry = 0; ry < RY; ++ry)
                            #pragma unroll
                            for (int nx = 0; nx < NX; ++nx)
                                acc[mt][ry][nx] = __builtin_amdgcn_mfma_f32_16x16x32_bf16(alf[mt], bh[ry][nx], acc[mt][ry][nx], 0, 0, 0);
                }
            }
        }
    }

    #pragma unroll
    for (int ry = 0; ry < RY; ++ry) {
        int yo = y0 + ry;
        #pragma unroll
        for (int nx = 0; nx < NX; ++nx) {
            int xo = nx * 16 + n_l;
            size_t vb = ((((size_t)b * DO + z) * DO + yo) * (DO + 1)) * CVO + CVO + (size_t)xo * CVO;
            float mval = 1.f;
            if (EPI & EPI_MASK) mval = mask[(((size_t)b * DO + z) * DO + yo) * DO + xo];
            #pragma unroll
            for (int mt = 0; mt < NCT; ++mt) {
                int c0 = (mt0 + mt) * 16 + q * 4;
                size_t oa = vb + choff(c0);
                float rs[4] = {0.f, 0.f, 0.f, 0.f};
                if (EPI & EPI_RESID) {
                    us4 rh4 = *(const us4*)(resid + oa);
                    us4 rl4 = *(const us4*)(resid + oa + 8);
                    #pragma unroll
                    for (int r = 0; r < 4; ++r) rs[r] = bf2f(rh4[r]) + bf2f(rl4[r]);
                }
                us4 oh, ol;
                #pragma unroll
                for (int r = 0; r < 4; ++r) {
                    float v = acc[mt][ry][nx][r];
                    if (EPI & EPI_MASK) v *= mval;
                    if (EPI & EPI_RESID) v += rs[r];
                    if (EPI & EPI_LEAKY) v = leaky(v);
                    ushort hb = f2bf(v);
                    oh[r] = hb;
                    ol[r] = f2bf(v - bf2f(hb));
                }
                *(us4*)(outp + oa) = oh;
                *(us4*)(outp + oa + 8) = ol;
            }
        }
    }
}

// ---------------- MFMA conv v8: stage-2 convs (S=1), slab staging -------------
template<int CI, int CO, int DI, int RY, int NX, int NCT, int WPEU, int EPI>
__global__ __launch_bounds__(256, WPEU) void mfma_conv8_kernel(
    const ushort* __restrict__ inp, const ushort* __restrict__ A,
    const float* __restrict__ mask, const ushort* __restrict__ resid,
    ushort* __restrict__ outp)
{
    constexpr int DO = DI;
    constexpr int NCI = CI / 32;
    constexpr int NMT = CO / 16;
    constexpr int CV = CI * 2;
    constexpr int CVO = CO * 2;
    constexpr int YG = DO / RY;
    constexpr int NYR = RY + 2;
    constexpr int NXV = DO + 2;
    constexpr int LVS = 72;
    constexpr int NGRP = NYR * NXV * 8;

    __shared__ ushort sB[NYR * NXV * LVS];

    const int rg = (blockIdx.x & 7) * ((int)gridDim.x >> 3) + (blockIdx.x >> 3);
    const int y0 = (rg % YG) * RY;
    const int z = (rg / YG) % DO;
    const int b = rg / (YG * DO);
    const int wave = threadIdx.x >> 6;
    const int lane = threadIdx.x & 63;
    const int n_l = lane & 15;
    const int q = lane >> 4;
    const int mt0 = (blockIdx.y * 4 + wave) * NCT;

    f32x4 acc[NCT][RY][NX];
    #pragma unroll
    for (int a = 0; a < NCT; ++a)
        #pragma unroll
        for (int r = 0; r < RY; ++r)
            #pragma unroll
            for (int c = 0; c < NX; ++c)
                acc[a][r][c] = (f32x4){0.f, 0.f, 0.f, 0.f};

    #pragma unroll 1
    for (int ct = 0; ct < NCI; ++ct) {
        #pragma unroll 1
        for (int dz = 0; dz < 3; ++dz) {
            int zp = z + dz - 1;
            bool vz = (unsigned)zp < (unsigned)DI;
            int zpc = vz ? zp : 0;
            __syncthreads();
            for (int g = threadIdx.x; g < NGRP; g += 256) {
                int r = g / (NXV * 8);
                int rem = g - r * (NXV * 8);
                int xv = rem >> 3;
                int gg = rem & 7;
                int yp = y0 + r - 1;
                bool v = vz & ((unsigned)yp < (unsigned)DI);
                long src = v ? ((((((long)b * DI + zpc) * DI + yp) * (DI + 1)) * CV + CV)
                                + (long)(xv - 1) * CV + ct * 64 + gg * 8)
                             : (long)(ct * 64 + gg * 8);   // zeroed lead pad
                *(bf16x8*)(sB + (r * NXV + xv) * LVS + gg * 8) = *(const bf16x8*)(inp + src);
            }
            __syncthreads();
            #pragma unroll 1
            for (int dy = 0; dy < 3; ++dy) {
                #pragma unroll
                for (int dx = 0; dx < 3; ++dx) {
                    const int tap = dz * 9 + dy * 3 + dx;
                    bf16x8 bh[RY][NX], bl[RY][NX];
                    #pragma unroll
                    for (int ry = 0; ry < RY; ++ry)
                        #pragma unroll
                        for (int nx = 0; nx < NX; ++nx) {
                            int xv = nx * 16 + n_l + dx;
                            const ushort* p = sB + ((ry + dy) * NXV + xv) * LVS + q * 16;
                            bh[ry][nx] = *(const bf16x8*)p;
                            bl[ry][nx] = *(const bf16x8*)(p + 8);
                        }
                    bf16x8 ahf[NCT], alf[NCT];
                    #pragma unroll
                    for (int mt = 0; mt < NCT; ++mt) {
                        size_t aa = ((size_t)(tap * NCI + ct) * NMT + (mt0 + mt)) * 1024 + lane * 16;
                        ahf[mt] = *(const bf16x8*)(A + aa);
                        alf[mt] = *(const bf16x8*)(A + aa + 8);
                    }
                    #pragma unroll
                    for (int mt = 0; mt < NCT; ++mt)
                        #pragma unroll
                        for (int ry = 0; ry < RY; ++ry)
                            #pragma unroll
                            for (int nx = 0; nx < NX; ++nx)
                                acc[mt][ry][nx] = __builtin_amdgcn_mfma_f32_16x16x32_bf16(ahf[mt], bh[ry][nx], acc[mt][ry][nx], 0, 0, 0);
                    #pragma unroll
                    for (int mt = 0; mt < NCT; ++mt)
                        #pragma unroll
                        for (int ry = 0; ry < RY; ++ry)
                            #pragma unroll
                            for (int nx = 0; nx < NX; ++nx)
                                acc[mt][ry][nx] = __builtin_amdgcn_mfma_f32_16x16x32_bf16(ahf[mt], bl[ry][nx], acc[mt][ry][nx], 0, 0, 0);
                    #pragma unroll
                    for (int mt = 0; mt < NCT; ++mt)
                        #pragma unroll
                        for (int ry = 0; ry < RY; ++ry)
                            #pragma unroll
                            for (int nx = 0; nx < NX; ++nx)
                                acc[mt][ry][nx] = __builtin_amdgcn_mfma_f32_16x16x32_bf16(alf[mt], bh[ry][nx], acc[mt][ry][nx], 0, 0, 0);
                }
            }
        }
    }

    #pragma unroll
    for (int ry = 0; ry < RY; ++ry) {
        int yo = y0 + ry;
        #pragma unroll
        for (int nx = 0; nx < NX; ++nx) {
            int xo = nx * 16 + n_l;
            size_t vb = ((((size_t)b * DO + z) * DO + yo) * (DO + 1)) * CVO + CVO + (size_t)xo * CVO;
            float mval = 1.f;
            if (EPI & EPI_MASK) mval = mask[(((size_t)b * DO + z) * DO + yo) * DO + xo];
            #pragma unroll
            for (int mt = 0; mt < NCT; ++mt) {
                int c0 = (mt0 + mt) * 16 + q * 4;
                size_t oa = vb + choff(c0);
                float rs[4] = {0.f, 0.f, 0.f, 0.f};
                if (EPI & EPI_RESID) {
                    us4 rh4 = *(const us4*)(resid + oa);
                    us4 rl4 = *(const us4*)(resid + oa + 8);
                    #pragma unroll
                    for (int r = 0; r < 4; ++r) rs[r] = bf2f(rh4[r]) + bf2f(rl4[r]);
                }
                us4 oh, ol;
                #pragma unroll
                for (int r = 0; r < 4; ++r) {
                    float v = acc[mt][ry][nx][r];
                    if (EPI & EPI_MASK) v *= mval;
                    if (EPI & EPI_RESID) v += rs[r];
                    if (EPI & EPI_LEAKY) v = leaky(v);
                    ushort hb = f2bf(v);
                    oh[r] = hb;
                    ol[r] = f2bf(v - bf2f(hb));
                }
                *(us4*)(outp + oa) = oh;
                *(us4*)(outp + oa + 8) = ol;
            }
        }
    }
}

// ---------------- MFMA conv v7: stage-3 convs (S=1, DO=16), K-split ----------
template<int CI, int CO, int DI, int RY, int NCT, int KS, int WPEU>
__global__ __launch_bounds__(256, WPEU) void mfma_conv7_kernel(
    const ushort* __restrict__ inp, const ushort* __restrict__ A,
    float* __restrict__ part)
{
    constexpr int DO = DI;
    constexpr int NCI = CI / 32;
    constexpr int KCI = NCI / KS;
    constexpr int NMT = CO / 16;
    constexpr int CV = CI * 2;
    constexpr int YG = DO / RY;
    constexpr int NYR = RY + 2;
    constexpr int NXV = DO + 2;
    constexpr int LVS = 72;
    constexpr int NCOG = NMT / (4 * NCT);
    constexpr int D3 = DO * DO * DO;

    __shared__ ushort sB[3 * NYR * NXV * LVS];

    const int rg = (blockIdx.x & 7) * ((int)gridDim.x >> 3) + (blockIdx.x >> 3);
    const int y0 = (rg % YG) * RY;
    const int z = (rg / YG) % DO;
    const int b = rg / (YG * DO);
    const int wave = threadIdx.x >> 6;
    const int lane = threadIdx.x & 63;
    const int n_l = lane & 15;
    const int q = lane >> 4;
    const int cog = blockIdx.y % NCOG;
    const int kc = blockIdx.y / NCOG;
    const int mt0 = (cog * 4 + wave) * NCT;

    f32x4 acc[NCT][RY];
    #pragma unroll
    for (int a = 0; a < NCT; ++a)
        #pragma unroll
        for (int r = 0; r < RY; ++r)
            acc[a][r] = (f32x4){0.f, 0.f, 0.f, 0.f};

    #pragma unroll 1
    for (int ctl = 0; ctl < KCI; ++ctl) {
        const int ct = kc * KCI + ctl;
        __syncthreads();
        for (int g = threadIdx.x; g < 3 * NYR * NXV * 8; g += 256) {
            int row = g / (NXV * 8);
            int rem = g - row * (NXV * 8);
            int xv = rem >> 3;
            int gg = rem & 7;
            int zi = row / NYR, yr = row - zi * NYR;
            int zp = z + zi - 1;
            int yp = y0 + yr - 1;
            bool v = ((unsigned)zp < (unsigned)DI) & ((unsigned)yp < (unsigned)DI);
            long src = v ? ((((((long)b * DI + zp) * DI + yp) * (DI + 1)) * CV + CV)
                            + (long)(xv - 1) * CV + ct * 64 + gg * 8)
                         : (long)(ct * 64 + gg * 8);
            *(bf16x8*)(sB + (row * NXV + xv) * LVS + gg * 8) = *(const bf16x8*)(inp + src);
        }
        __syncthreads();
        #pragma unroll 1
        for (int dz = 0; dz < 3; ++dz) {
            #pragma unroll 1
            for (int dy = 0; dy < 3; ++dy) {
                #pragma unroll
                for (int dx = 0; dx < 3; ++dx) {
                    const int tap = dz * 9 + dy * 3 + dx;
                    bf16x8 bh[RY], bl[RY];
                    #pragma unroll
                    for (int ry = 0; ry < RY; ++ry) {
                        const ushort* p = sB + ((dz * NYR + ry + dy) * NXV + n_l + dx) * LVS + q * 16;
                        bh[ry] = *(const bf16x8*)p;
                        bl[ry] = *(const bf16x8*)(p + 8);
                    }
                    bf16x8 ahf[NCT], alf[NCT];
                    #pragma unroll
                    for (int mt = 0; mt < NCT; ++mt) {
                        size_t aa = ((size_t)(tap * NCI + ct) * NMT + (mt0 + mt)) * 1024 + lane * 16;
                        ahf[mt] = *(const bf16x8*)(A + aa);
                        alf[mt] = *(const bf16x8*)(A + aa + 8);
                    }
                    #pragma unroll
                    for (int mt = 0; mt < NCT; ++mt)
                        #pragma unroll
                        for (int ry = 0; ry < RY; ++ry)
                            acc[mt][ry] = __builtin_amdgcn_mfma_f32_16x16x32_bf16(ahf[mt], bh[ry], acc[mt][ry], 0, 0, 0);
                    #pragma unroll
                    for (int mt = 0; mt < NCT; ++mt)
                        #pragma unroll
                        for (int ry = 0; ry < RY; ++ry)
                            acc[mt][ry] = __builtin_amdgcn_mfma_f32_16x16x32_bf16(ahf[mt], bl[ry], acc[mt][ry], 0, 0, 0);
                    #pragma unroll
                    for (int mt = 0; mt < NCT; ++mt)
                        #pragma unroll
                        for (int ry = 0; ry < RY; ++ry)
                            acc[mt][ry] = __builtin_amdgcn_mfma_f32_16x16x32_bf16(alf[mt], bh[ry], acc[mt][ry], 0, 0, 0);
                }
            }
        }
    }

    #pragma unroll
    for (int ry = 0; ry < RY; ++ry) {
        int yo = y0 + ry;
        int v = (z * DO + yo) * DO + n_l;
        #pragma unroll
        for (int mt = 0; mt < NCT; ++mt) {
            int c0 = (mt0 + mt) * 16 + q * 4;
            size_t off = (((size_t)kc * 2 + b) * D3 + v) * CO + c0;
            *(f32x4*)(part + off) = acc[mt][ry];
        }
    }
}

// ---------------- combine3: sum K-split halves + epilogue -> interleaved CL ---
__global__ __launch_bounds__(256) void combine3_kernel(
    const float* __restrict__ part, const float* __restrict__ mask,
    const ushort* __restrict__ resid, ushort* __restrict__ outp)
{
    int i = blockIdx.x * 256 + threadIdx.x;      // over 2*4096*64
    if (i >= 2 * 4096 * 64) return;
    int g = i & 63, v = (i >> 6) & 4095, b = i >> 18;
    int c0 = g * 4;
    size_t p0 = (((size_t)b) * 4096 + v) * 256 + c0;
    float4 s0 = *(const float4*)(part + p0);
    float4 s1 = *(const float4*)(part + p0 + (size_t)2 * 4096 * 256);
    float m = mask[b * 4096 + v];
    int z = v >> 8, y = (v >> 4) & 15, x = v & 15;
    size_t vb = ((((size_t)b * 16 + z) * 16 + y) * 17) * 512 + 512 + (size_t)x * 512;
    size_t oa = vb + choff(c0);
    float rs[4] = {0.f, 0.f, 0.f, 0.f};
    if (resid) {
        us4 rh = *(const us4*)(resid + oa);
        us4 rl = *(const us4*)(resid + oa + 8);
        #pragma unroll
        for (int r = 0; r < 4; ++r) rs[r] = bf2f(rh[r]) + bf2f(rl[r]);
    }
    float sv[4] = {s0.x + s1.x, s0.y + s1.y, s0.z + s1.z, s0.w + s1.w};
    us4 oh, ol;
    #pragma unroll
    for (int r = 0; r < 4; ++r) {
        float val = sv[r] * m + rs[r];
        val = leaky(val);
        ushort hb = f2bf(val);
        oh[r] = hb;
        ol[r] = f2bf(val - bf2f(hb));
    }
    *(us4*)(outp + oa) = oh;
    *(us4*)(outp + oa + 8) = ol;
}

// ---------------- wd3 via MFMA (product-major) -> x4 fp32 ---------------------
__global__ __launch_bounds__(256) void wd3_mfma_kernel(
    const ushort* __restrict__ x3, const ushort* __restrict__ A,
    float* __restrict__ x4)
{
    constexpr int NCI = 8;   // 256/32
    constexpr int NMT = 8;   // 128/16
    const int blk = blockIdx.x;
    const int yg = blk & 3;
    const int z = (blk >> 2) & 7;
    const int b = blk >> 5;
    const int wave = threadIdx.x >> 6;
    const int lane = threadIdx.x & 63;
    const int n_l = lane & 15;
    const int q = lane >> 4;
    const int y = yg * 2 + (n_l >> 3);
    const int x = n_l & 7;
    const int mt0 = wave * 2;

    f32x4 acc[2];
    acc[0] = (f32x4){0.f, 0.f, 0.f, 0.f};
    acc[1] = (f32x4){0.f, 0.f, 0.f, 0.f};
    const bf16x8 zero8 = {0, 0, 0, 0, 0, 0, 0, 0};

    for (int ct = 0; ct < NCI; ++ct) {
        #pragma unroll
        for (int dz = 0; dz < 3; ++dz) {
            int zp = 2 * z + dz - 1;
            if ((unsigned)zp >= 16u) continue;
            #pragma unroll
            for (int dy = 0; dy < 3; ++dy) {
                int yp = 2 * y + dy - 1;
                bool vy = (unsigned)yp < 16u;
                int ypc = vy ? yp : 0;
                #pragma unroll
                for (int dx = 0; dx < 3; ++dx) {
                    int xp = 2 * x + dx - 1;
                    int tap = dz * 9 + dy * 3 + dx;
                    size_t ba = ((((size_t)b * 16 + zp) * 16 + ypc) * 17 + 1 + xp) * 512
                              + ct * 64 + q * 16;
                    bf16x8 bh = vy ? *(const bf16x8*)(x3 + ba) : zero8;
                    bf16x8 bl = vy ? *(const bf16x8*)(x3 + ba + 8) : zero8;
                    bf16x8 ahf[2], alf[2];
                    #pragma unroll
                    for (int mt = 0; mt < 2; ++mt) {
                        size_t aa = ((size_t)(tap * NCI + ct) * NMT + (mt0 + mt)) * 1024 + lane * 16;
                        ahf[mt] = *(const bf16x8*)(A + aa);
                        alf[mt] = *(const bf16x8*)(A + aa + 8);
                    }
                    #pragma unroll
                    for (int mt = 0; mt < 2; ++mt)
                        acc[mt] = __builtin_amdgcn_mfma_f32_16x16x32_bf16(ahf[mt], bh, acc[mt], 0, 0, 0);
                    #pragma unroll
                    for (int mt = 0; mt < 2; ++mt)
                        acc[mt] = __builtin_amdgcn_mfma_f32_16x16x32_bf16(ahf[mt], bl, acc[mt], 0, 0, 0);
                    #pragma unroll
                    for (int mt = 0; mt < 2; ++mt)
                        acc[mt] = __builtin_amdgcn_mfma_f32_16x16x32_bf16(alf[mt], bh, acc[mt], 0, 0, 0);
                }
            }
        }
    }
    #pragma unroll
    for (int mt = 0; mt < 2; ++mt)
        #pragma unroll
        for (int r = 0; r < 4; ++r) {
            int co = (mt0 + mt) * 16 + q * 4 + r;
            x4[((size_t)(b * 128 + co)) * 512 + z * 64 + y * 8 + x] = leaky(acc[mt][r]);
        }
}

// ---------------- final: mean/max pool over 8^3 -------------------------------
__global__ __launch_bounds__(64) void reduce_kernel(
    const float* __restrict__ x4, float* __restrict__ out)
{
    int bc = blockIdx.x;
    int b = bc >> 7, c = bc & 127;
    const float* p = x4 + (size_t)(b * 128 + c) * 512;
    float s = 0.f, mx = -3.4e38f;
    for (int i = threadIdx.x; i < 512; i += 64) {
        float v = p[i];
        s += v;
        mx = fmaxf(mx, v);
    }
    #pragma unroll
    for (int o = 32; o > 0; o >>= 1) {
        s += __shfl_down(s, o);
        mx = fmaxf(mx, __shfl_down(mx, o));
    }
    if (threadIdx.x == 0) {
        out[b * 256 + c] = s * (1.f / 512.f);
        out[b * 256 + 128 + c] = mx;
    }
}

__global__ __launch_bounds__(256) void zero_out_kernel(float* __restrict__ out, int n)
{
    int i = blockIdx.x * 256 + threadIdx.x;
    if (i < n) out[i] = 0.f;
}

// ---------------------------------------------------------------------------
extern "C" void kernel_launch(void* const* d_in, const int* in_sizes, int n_in,
                              void* d_out, int out_size, void* d_ws, size_t ws_size,
                              hipStream_t stream)
{
    (void)in_sizes; (void)n_in;
    const float* x    = (const float*)d_in[0];
    const float* mask = (const float*)d_in[1];
    const float* w1a  = (const float*)d_in[2];
    const float* w1b  = (const float*)d_in[3];
    const float* w1d  = (const float*)d_in[4];
    const float* wd1  = (const float*)d_in[5];
    const float* w2a  = (const float*)d_in[6];
    const float* w2b  = (const float*)d_in[7];
    const float* wd2  = (const float*)d_in[8];
    const float* w3a  = (const float*)d_in[9];
    const float* w3b  = (const float*)d_in[10];
    const float* wd3  = (const float*)d_in[11];
    float* out = (float*)d_out;
    char* ws = (char*)d_ws;

    const size_t RSZ = 34603520;      // stage-2 tensor region (interleaved)
    const size_t POFF = 9437184;      // partial-buffer offset within R2/R3
    char* R1 = ws;
    char* R2 = ws + RSZ;
    char* R3 = ws + 2 * RSZ;
    size_t off = 3 * RSZ;
    auto alloc = [&](size_t bytes) { char* p = ws + off; off = (off + bytes + 255) & ~255ull; return p; };
    ushort* pk2a = (ushort*)alloc(1769472);
    ushort* pk2b = (ushort*)alloc(1769472);
    ushort* pkd2 = (ushort*)alloc(3538944);
    ushort* pk3a = (ushort*)alloc(7077888);
    ushort* pk3b = (ushort*)alloc(7077888);
    float*  wd1P = (float*)alloc(884736);
    float*  waT  = (float*)alloc(20736);
    float*  w1bT = (float*)alloc(442368);
    float*  wdTt = (float*)alloc(768);
    float*  m2   = (float*)alloc(262144);
    float*  m3   = (float*)alloc(32768);
    int*    cnt  = (int*)alloc(256);
    const size_t NEED = off;

    if (ws_size < NEED) {
        zero_out_kernel<<<dim3((out_size + 255) / 256), 256, 0, stream>>>(out, out_size);
        return;
    }

    // stage-1 scratch aliased into R2 (dead before t2 is written)
    float* t1c  = (float*)R2;
    float* x1c  = (float*)(R2 + 8388608);
    int*   idx  = (int*)(R2 + 16777216);
    int*   list = (int*)(R2 + 18874368);
    // late-phase aliases
    ushort* pkd3 = (ushort*)R1;       // xin3 dead after conv3b combine
    float*  x4   = (float*)R2;        // t3 dead after conv3b conv
    float*  part3a = (float*)(R2 + POFF);
    float*  part3b = (float*)(R3 + POFF);

    ushort* xin2 = (ushort*)R1;
    ushort* t2   = (ushort*)R2;
    ushort* x2   = (ushort*)R3;
    ushort* xin3 = (ushort*)R1;
    ushort* t3   = (ushort*)R2;
    ushort* x3   = (ushort*)R3;

    hipMemsetAsync(cnt, 0, 4, stream);
    hipMemsetAsync(idx, 0xFF, 2097152, stream);
    // xin2 pads (R1 only; R2/R3 pads after stage-1 scratch dies)
    pad_zero_kernel<<<dim3((2049 * 32 + 255) / 256), 256, 0, stream>>>(
        (ushort*)R1, 2048, 33 * 256, 256);

    // batched weight prep (5 MFMA packs + 4 stage-1 preps = 2 launches)
    pack5_kernel<<<dim3((10616832 + 255) / 256), 256, 0, stream>>>(
        w2a, pk2a, w2b, pk2b, wd2, pkd2, w3a, pk3a, w3b, pk3b);
    pack_s1_kernel<<<dim3((337152 + 255) / 256), 256, 0, stream>>>(
        wd1, wd1P, w1a, waT, w1b, w1bT, w1d, wdTt);

    // fused build_list + maxpool64->32, then m2->m3
    mask_front_kernel<<<dim3((589824 + 255) / 256), 256, 0, stream>>>(
        mask, list, idx, cnt, m2);
    maxpool_kernel<32, 16><<<dim3(2 * 4096 / 256), 256, 0, stream>>>(m2, m3);

    // stage 1 (sparse, fp32)
    stage1a_kernel<<<dim3(2048), 64, 0, stream>>>(x, waT, list, cnt, t1c);
    stage1b_kernel<<<dim3(ROWCAP), 64, 0, stream>>>(t1c, x, w1bT, wdTt, list, idx, cnt, x1c);
    wd1_kernel<<<dim3(32768, 2), 128, 0, stream>>>(x1c, idx, wd1P, xin2);

    // stage-1 scratch dead; zero t2/x2 pads (one launch)
    pad_zero2_kernel<<<dim3((2 * 2049 * 32 + 255) / 256), 256, 0, stream>>>(
        (ushort*)R2, (ushort*)R3, 2048, 33 * 256, 256);

    // stage2 res block: conv8 slab staging (RY=2/NX=2/NCT=2, 1024 blocks)
    mfma_conv8_kernel<128, 128, 32, 2, 2, 2, 4, EPI_MASK | EPI_LEAKY>
        <<<dim3(1024, 1), 256, 0, stream>>>(xin2, pk2a, m2, nullptr, t2);
    mfma_conv8_kernel<128, 128, 32, 2, 2, 2, 4, EPI_MASK | EPI_RESID | EPI_LEAKY>
        <<<dim3(1024, 1), 256, 0, stream>>>(t2, pk2b, m2, xin2, x2);

    // xin2/t2 dead -> zero xin3 + t3 pads (one launch); wd2 (conv6)
    pad_zero2_kernel<<<dim3((2 * 513 * 64 + 255) / 256), 256, 0, stream>>>(
        (ushort*)R1, (ushort*)R2, 512, 17 * 512, 512);
    mfma_conv6_kernel<128, 256, 32, 16, 2, 2, 1, 2, 4, EPI_LEAKY>
        <<<dim3(256, 2), 256, 0, stream>>>(x2, pkd2, nullptr, nullptr, xin3);

    // conv3a: conv7 (K-split) -> partials; combine -> t3
    mfma_conv7_kernel<256, 256, 16, 2, 2, 2, 4>
        <<<dim3(256, 4), 256, 0, stream>>>(xin3, pk3a, part3a);
    combine3_kernel<<<dim3(2048), 256, 0, stream>>>(part3a, m3, nullptr, t3);

    // x2 dead after wd2 -> zero x3 pads; conv3b -> partials; combine -> x3
    pad_zero_kernel<<<dim3((513 * 64 + 255) / 256), 256, 0, stream>>>(
        (ushort*)R3, 512, 17 * 512, 512);
    mfma_conv7_kernel<256, 256, 16, 2, 2, 2, 4>
        <<<dim3(256, 4), 256, 0, stream>>>(t3, pk3b, part3b);
    combine3_kernel<<<dim3(2048), 256, 0, stream>>>(part3b, m3, xin3, x3);

    // xin3 (R1) and t3 (R2) dead: pack wd3 -> R1, MFMA wd3 -> x4 (R2)
    pack_w_kernel<<<dim3((27 * 256 * 128 * 2 + 255) / 256), 256, 0, stream>>>(wd3, pkd3, 256, 128);
    wd3_mfma_kernel<<<dim3(64), 256, 0, stream>>>(x3, pkd3, x4);

    reduce_kernel<<<dim3(256), 64, 0, stream>>>(x4, out);
}